// Round 15
// baseline (7117.143 us; speedup 1.0000x reference)
//
#include <hip/hip_runtime.h>
#include <hip/hip_bf16.h>
#include <math.h>

#define B 64
#define T 160
#define P 196
#define ENC 2048
#define ATT 512
#define EMB 512
#define HID 1024
#define KTOT 3584   // EMB + ENC + HID
#define N2 2560     // ATT + ENC
#define KT4 112     // KTOT/32
#define NTHR 1024
#define NBLK 256
#define NGRP 16
#define GRPSZ (NBLK/NGRP)

// barrier word-offsets (unsigned words), 256B (64-word) stride per slot
#define ARR_W 0            // 256 arrival slots
#define GD_W  16384        // 16 group-done slots
#define REL_W 17408        // 16 release slots

typedef __attribute__((ext_vector_type(8))) short bf16x8;
typedef __attribute__((ext_vector_type(4))) float f32x4;
typedef float __attribute__((ext_vector_type(4))) vf4;

__device__ __forceinline__ float sigm(float x){ return 1.0f/(1.0f+__expf(-x)); }
__device__ __forceinline__ float bfu(short s){ return __uint_as_float(((unsigned)(unsigned short)s) << 16); }

// ---- MALL-coherent movement for cross-block data (volatile => sc0 sc1) ----
__device__ __forceinline__ float ldgf(const float* p){ return *(const volatile float*)p; }
__device__ __forceinline__ void stgf(float* p, float v){ *(volatile float*)p = v; }
__device__ __forceinline__ void stgu(unsigned* p, unsigned v){ *(volatile unsigned*)p = v; }
__device__ __forceinline__ unsigned pkbf(float a, float b){
    unsigned ua = (unsigned)__bfloat16_as_ushort(__float2bfloat16(a));
    unsigned ub = (unsigned)__bfloat16_as_ushort(__float2bfloat16(b));
    return ua | (ub << 16);
}

// ---- store-based grid barrier: parallel arrival stores + wave-swept detection ----
__device__ __forceinline__ void gbar_arrive(unsigned* bar, unsigned k){
    asm volatile("s_waitcnt vmcnt(0)" ::: "memory");   // data stores acked before arrival flag
    __syncthreads();
    if (threadIdx.x == 0)
        *(volatile unsigned*)(bar + ARR_W + (unsigned)blockIdx.x*64) = k + 1u;
}
__device__ __forceinline__ void gbar_wait(unsigned* bar, unsigned k){
    int b = blockIdx.x, tid = threadIdx.x;
    if (b < NGRP){
        if (tid < 64){
            // sweep my group's 16 arrival slots (members: m*16 + b)
            volatile unsigned* s = (volatile unsigned*)(bar + ARR_W + (unsigned)((tid & 15)*NGRP + b)*64);
            while (!__all(*s >= k + 1u)) __builtin_amdgcn_s_sleep(1);
            if (tid == 0) *(volatile unsigned*)(bar + GD_W + b*64) = k + 1u;
            // sweep all 16 group-done slots
            volatile unsigned* g = (volatile unsigned*)(bar + GD_W + (tid & 15)*64);
            while (!__all(*g >= k + 1u)) __builtin_amdgcn_s_sleep(1);
            if (tid == 0) *(volatile unsigned*)(bar + REL_W + b*64) = k + 1u;
        }
    } else {
        if (tid == 0){
            volatile unsigned* r = (volatile unsigned*)(bar + REL_W + (b & (NGRP-1))*64);
            while (*r < k + 1u) __builtin_amdgcn_s_sleep(1);
        }
    }
    __syncthreads();
    asm volatile("" ::: "memory");
}
__device__ __forceinline__ void gbar(unsigned* bar, unsigned k){
    gbar_arrive(bar, k);
    gbar_wait(bar, k);
}

// ---------- sort + nAct table ----------
__global__ void k_sort(const int* lens, int* idx, int* rank, unsigned* barCnt, int* nAct){
    __shared__ int L[B];
    int i = threadIdx.x;
    L[i] = lens[i];
    for (int s = i; s < 288; s += B){
        int wofs = (s < 256) ? (ARR_W + s*64)
                 : (s < 272) ? (GD_W + (s-256)*64)
                             : (REL_W + (s-272)*64);
        barCnt[wofs] = 0u;
    }
    __syncthreads();
    int li = L[i];
    int r = 0;
    for (int j = 0; j < B; ++j){
        int lj = L[j];
        if (lj > li || (lj == li && j < i)) r++;
    }
    rank[i] = r;
    idx[r] = i;
    for (int tt = i; tt < T; tt += B){
        int c = 0;
        for (int j = 0; j < B; ++j) c += (L[j] > tt) ? 1 : 0;
        nAct[tt] = c;
    }
}

// ---------- init h0/c0 (sorted) + bf16 copy into hbR slot 0 ----------
__global__ void k_init_hc(const float* enc_h, const float* enc_c, const int* idx,
                          float* h, float* c, __hip_bfloat16* hbR0){
    int j = blockIdx.x;
    int o = idx[j];
    for (int k = threadIdx.x; k < HID; k += blockDim.x){
        float hv = (k < 512) ? enc_h[o*512 + k] : enc_h[B*512 + o*512 + (k-512)];
        float cv = (k < 512) ? enc_c[o*512 + k] : enc_c[B*512 + o*512 + (k-512)];
        h[j*HID + k] = hv;
        c[j*HID + k] = cv;
        hbR0[j*HID + k] = __float2bfloat16(hv);
    }
}

// ---------- Wcat in per-strip MFMA-fragment order (once) ----------
__global__ void k_cvt_wcat(const float* Wih, const float* Whh, __hip_bfloat16* Wfrag){
    size_t i = (size_t)blockIdx.x*256 + threadIdx.x;
    int e = (int)(i & 7);
    size_t t2 = i >> 3;
    int lane = (int)(t2 & 63);
    size_t t3 = t2 >> 6;
    int kt = (int)(t3 % KT4);
    int strip = (int)(t3 / KT4);
    int n = strip*16 + (lane & 15);
    int r = (n & 3)*HID + (n >> 2);
    int k = kt*32 + (lane >> 4)*8 + e;
    float v = (k < EMB+ENC) ? Wih[(size_t)r*(EMB+ENC) + k]
                            : Whh[(size_t)r*HID + (k - EMB - ENC)];
    Wfrag[i] = __float2bfloat16(v);
}

__global__ void k_bsum(const float* bih, const float* bhh, float* bsum){
    int n = blockIdx.x*256 + threadIdx.x;
    int r = (n & 3)*HID + (n >> 2);
    bsum[n] = bih[r] + bhh[r];
}

__global__ void k_cvt_w2(const float* Wda, const float* bda, const float* Wfb, const float* bfb,
                         __hip_bfloat16* W2, float* bias2){
    int n = blockIdx.x;
    const float* src = (n < ATT) ? (Wda + (size_t)n*HID) : (Wfb + (size_t)(n-ATT)*HID);
    __hip_bfloat16* dst = W2 + (size_t)n*HID;
    for (int k = threadIdx.x; k < HID; k += 256) dst[k] = __float2bfloat16(src[k]);
    if (threadIdx.x == 0) bias2[n] = (n < ATT) ? bda[n] : bfb[n-ATT];
}

__global__ void k_cvt_emb(const float* emb, __hip_bfloat16* emb_bf){
    size_t i = (size_t)blockIdx.x*256 + threadIdx.x;
    emb_bf[i] = __float2bfloat16(emb[i]);
}

__global__ void k_cvt_wea(const float* Wea, __hip_bfloat16* Wea_bf){
    int n = blockIdx.x;
    for (int k = threadIdx.x; k < ENC; k += 256)
        Wea_bf[(size_t)n*ENC + k] = __float2bfloat16(Wea[(size_t)n*ENC + k]);
}

__global__ void k_cvt_img(const float* img, const int* idx, __hip_bfloat16* img_s){
    int j = blockIdx.y;
    int o = idx[j];
    size_t off = (size_t)blockIdx.x*256 + threadIdx.x;
    img_s[(size_t)j*P*ENC + off] = __float2bfloat16(img[(size_t)o*P*ENC + off]);
}

// ---------- att1 (once, MFMA) ----------
__global__ __launch_bounds__(256) void k_att1m(const __hip_bfloat16* img_s, const __hip_bfloat16* Wea_bf,
                                               const float* bea, __hip_bfloat16* att1w){
    int m0 = blockIdx.x * 64, n0 = blockIdx.y * 64;
    int tid = threadIdx.x, w = tid >> 6, l = tid & 63, lm = l & 15, lk = l >> 4;
    const short* ap = (const short*)img_s + (size_t)(m0 + 16*w + lm)*ENC + 8*lk;
    const short* bp = (const short*)Wea_bf + (size_t)(n0 + lm)*ENC + 8*lk;
    f32x4 acc[4];
    #pragma unroll
    for (int nt=0; nt<4; ++nt) acc[nt] = (f32x4){0.f,0.f,0.f,0.f};
    #pragma unroll 4
    for (int kt = 0; kt < ENC/32; ++kt){
        bf16x8 a = *(const bf16x8*)(ap + kt*32);
        #pragma unroll
        for (int nt=0; nt<4; ++nt){
            bf16x8 bb = *(const bf16x8*)(bp + (size_t)nt*16*ENC + kt*32);
            acc[nt] = __builtin_amdgcn_mfma_f32_16x16x32_bf16(a, bb, acc[nt], 0,0,0);
        }
    }
    #pragma unroll
    for (int nt=0; nt<4; ++nt){
        int n = n0 + nt*16 + lm;
        float bv = bea[n];
        #pragma unroll
        for (int r=0; r<4; ++r){
            int m = m0 + 16*w + 4*lk + r;
            att1w[(size_t)m*ATT + n] = __float2bfloat16(acc[nt][r] + bv);
        }
    }
}

// ---------- persistent cooperative scan ----------
struct SP {
    const __hip_bfloat16 *att1w, *img_s, *emb_bf, *Wfrag, *W2;
    const float *bsum, *bias2, *wfa, *bfa;
    const int *sent, *idx, *rank, *lens, *nAct;
    float *D2;
    __hip_bfloat16 *gcR, *hbR;     // rotating: gcR[t], hbR[t] (hbR has T+1 slots)
    float *hF0, *hF1, *cW;
    float *outH, *outA;
    unsigned *barCnt;
};

__global__ __launch_bounds__(1024, 4) void k_scan(SP p){
    __shared__ short WcatL[KT4*64*8];          // 114,688 B, fragment-ordered
    __shared__ union {
        struct { float Dp[4][64][17]; float hS[64][4]; int tokL[64], lensL[64], wLs[64]; } gem;
        struct { float att2L[512]; float wfaL[512]; float red[1024]; float aL[208]; float ctxP[8][512]; } p23;
    } sh;

    int b = blockIdx.x, tid = threadIdx.x;
    int w = tid >> 6, l = tid & 63, lm = l & 15, lk = l >> 4;
    unsigned bk = 0;

    // one-time LDS fill (straight copy, frag order)
    {
        const bf16x8* src = (const bf16x8*)((const short*)p.Wfrag + (size_t)b*KT4*64*8);
        bf16x8* dst = (bf16x8*)WcatL;
        #pragma unroll
        for (int i = 0; i < KT4*64/NTHR; ++i) dst[tid + i*NTHR] = src[tid + i*NTHR];
    }
    __syncthreads();

    float bfa0 = p.bfa[0];

    for (int t = 0; t < T; ++t){
        const __hip_bfloat16* hbIn = p.hbR + (size_t)t*B*HID;
        __hip_bfloat16*       hbOut = p.hbR + (size_t)(t+1)*B*HID;
        const __hip_bfloat16* gcT  = p.gcR + (size_t)t*B*ENC;
        const float* hFIn = (t & 1) ? p.hF1 : p.hF0;
        float*       hFOut = (t & 1) ? p.hF0 : p.hF1;
        int nAct = p.nAct[t];

        // ---- P1: D2[64][2560] = h_bf @ W2^T + bias2 ; blocks < 160, 4-way K-split ----
        if (b < N2/16){
            int n0 = b*16;
            int rt = w & 3, kq = w >> 2;
            if (16*rt < nAct){
                const short* ap = (const short*)hbIn + (size_t)(16*rt + lm)*HID + kq*256 + 8*lk;
                const short* bp = (const short*)p.W2 + (size_t)(n0 + lm)*HID + kq*256 + 8*lk;
                f32x4 acc = {0.f,0.f,0.f,0.f};
                #pragma unroll
                for (int kt = 0; kt < 8; ++kt){
                    bf16x8 a = *(const bf16x8*)(ap + kt*32);
                    bf16x8 bb = *(const bf16x8*)(bp + kt*32);
                    acc = __builtin_amdgcn_mfma_f32_16x16x32_bf16(a, bb, acc, 0,0,0);
                }
                #pragma unroll
                for (int r=0; r<4; ++r) sh.gem.Dp[kq][16*rt + 4*lk + r][lm] = acc[r];
            }
            __syncthreads();
            int m = tid >> 4, nl = tid & 15;
            if (m < nAct){
                stgf(&p.D2[m*N2 + n0 + nl],
                     sh.gem.Dp[0][m][nl] + sh.gem.Dp[1][m][nl]
                   + sh.gem.Dp[2][m][nl] + sh.gem.Dp[3][m][nl] + p.bias2[n0 + nl]);
            }
        }
        gbar(p.barCnt, bk); bk++;

        // ---- P23: e + softmax + context + gc ; block = (j=b&63, q=b>>6) ----
        int jj = b & 63, qq = b >> 6;
        int oo = p.idx[jj], wjj = p.rank[jj], ljj = p.lens[oo];
        {
            if (t < ljj){
                if (tid < 512){
                    sh.p23.att2L[tid] = ldgf(&p.D2[jj*N2 + tid]);
                    sh.p23.wfaL[tid]  = p.wfa[tid];
                }
                __syncthreads();

                int pp = tid & 255, ah = tid >> 8;
                float acc = 0.f;
                if (pp < P){
                    const short* ar = (const short*)p.att1w + (size_t)(jj*P + pp)*ATT + ah*128;
                    #pragma unroll 8
                    for (int k8 = 0; k8 < 16; ++k8){
                        bf16x8 v = *(const bf16x8*)(ar + k8*8);
                        #pragma unroll
                        for (int z=0; z<8; ++z){
                            int a = ah*128 + k8*8 + z;
                            acc += fmaxf(bfu(v[z]) + sh.p23.att2L[a], 0.f) * sh.p23.wfaL[a];
                        }
                    }
                }
                sh.p23.red[tid] = acc;
                __syncthreads();
                float e = -1e30f;
                if (tid < P) e = sh.p23.red[tid] + sh.p23.red[tid+256] + sh.p23.red[tid+512] + sh.p23.red[tid+768] + bfa0;
                __syncthreads();
                sh.p23.red[tid] = (tid < P) ? e : -1e30f;
                __syncthreads();
                for (int s = 512; s > 0; s >>= 1){
                    if (tid < s) sh.p23.red[tid] = fmaxf(sh.p23.red[tid], sh.p23.red[tid+s]);
                    __syncthreads();
                }
                float m = sh.p23.red[0];
                __syncthreads();
                float ex = (tid < P) ? __expf(e - m) : 0.f;
                sh.p23.red[tid] = ex;
                __syncthreads();
                for (int s = 512; s > 0; s >>= 1){
                    if (tid < s) sh.p23.red[tid] += sh.p23.red[tid+s];
                    __syncthreads();
                }
                float ssum = sh.p23.red[0];
                if (tid < P) sh.p23.aL[tid] = ex / ssum;
                if (tid >= P && tid < 208) sh.p23.aL[tid] = 0.f;
                __syncthreads();

                const short* ib = (const short*)p.img_s + (size_t)jj*P*ENC + qq*512 + l*8;
                float a8[8];
                #pragma unroll
                for (int z=0; z<8; ++z) a8[z] = 0.f;
                #pragma unroll 4
                for (int i = 0; i < 13; ++i){
                    int pp2 = w + 16*i;
                    int pr = (pp2 < P) ? pp2 : 0;
                    bf16x8 v = *(const bf16x8*)(ib + (size_t)pr*ENC);
                    float al = sh.p23.aL[pp2];
                    #pragma unroll
                    for (int z=0; z<8; ++z) a8[z] += al * bfu(v[z]);
                }
                if (w < 8){
                    #pragma unroll
                    for (int z=0; z<8; ++z) sh.p23.ctxP[w][l*8+z] = a8[z];
                }
                __syncthreads();
                if (w >= 8){
                    #pragma unroll
                    for (int z=0; z<8; ++z) sh.p23.ctxP[w-8][l*8+z] += a8[z];
                }
                __syncthreads();
                if (tid < 256){
                    int d0 = 2*tid;
                    float c0 = 0.f, c1 = 0.f;
                    #pragma unroll
                    for (int r=0; r<8; ++r){ c0 += sh.p23.ctxP[r][d0]; c1 += sh.p23.ctxP[r][d0+1]; }
                    int eg0 = qq*512 + d0;
                    float g0 = sigm(ldgf(&p.D2[jj*N2 + ATT + eg0]));
                    float g1 = sigm(ldgf(&p.D2[jj*N2 + ATT + eg0 + 1]));
                    stgu((unsigned*)((short*)gcT + jj*ENC + eg0), pkbf(g0*c0, g1*c1));
                }
            }
        }
        gbar_arrive(p.barCnt, bk);     // gc visible; do independent work in the wait shadow

        // outA write (external-only) in barrier shadow
        if (qq == 0 && tid < P){
            float av = (t < ljj) ? sh.p23.aL[tid] : 0.f;
            p.outA[((size_t)(wjj*T + t))*P + tid] = av;
        }
        __syncthreads();               // close p23 LDS usage before gem reuse

        // ---- P4 prelude + non-gc MFMA (emb + h segments) in barrier shadow ----
        if (tid < 64){
            int o = p.idx[tid];
            sh.gem.tokL[tid] = p.sent[o*T + t];
            sh.gem.lensL[tid] = p.lens[o];
            sh.gem.wLs[tid] = p.rank[tid];
        }
        __syncthreads();
        {
            int rt = w & 3, kq = w >> 2;
            bool act = (16*rt < nAct);
            int mrow = 16*rt + lm;
            f32x4 acc = {0.f,0.f,0.f,0.f};
            const short* aEmb = 0; const short* aGc = 0; const short* aH = 0;
            const bf16x8* BL = (const bf16x8*)WcatL;
            if (act){
                int tok = sh.gem.tokL[mrow];
                aEmb = (const short*)p.emb_bf + (size_t)tok*EMB + 8*lk;
                aGc  = (const short*)gcT + (size_t)mrow*ENC + 8*lk;
                aH   = (const short*)hbIn + (size_t)mrow*HID + 8*lk;
                if (kq == 0){
                    #pragma unroll 8
                    for (int kt = 0; kt < 16; ++kt){
                        bf16x8 a = *(const bf16x8*)(aEmb + kt*32);
                        acc = __builtin_amdgcn_mfma_f32_16x16x32_bf16(a, BL[kt*64 + l], acc, 0,0,0);
                    }
                } else if (kq == 2){
                    #pragma unroll
                    for (int kt = 80; kt < 84; ++kt){
                        bf16x8 a = *(const bf16x8*)(aH + (kt-80)*32);
                        acc = __builtin_amdgcn_mfma_f32_16x16x32_bf16(a, BL[kt*64 + l], acc, 0,0,0);
                    }
                } else if (kq == 3){
                    #pragma unroll 7
                    for (int kt = 84; kt < 112; ++kt){
                        bf16x8 a = *(const bf16x8*)(aH + (kt-80)*32);
                        acc = __builtin_amdgcn_mfma_f32_16x16x32_bf16(a, BL[kt*64 + l], acc, 0,0,0);
                    }
                }
            }
            gbar_wait(p.barCnt, bk); bk++;    // gc now ready

            if (act){
                if (kq == 0){
                    #pragma unroll 6
                    for (int kt = 16; kt < 28; ++kt){
                        bf16x8 a = *(const bf16x8*)(aGc + (kt-16)*32);
                        acc = __builtin_amdgcn_mfma_f32_16x16x32_bf16(a, BL[kt*64 + l], acc, 0,0,0);
                    }
                } else if (kq == 1){
                    #pragma unroll 7
                    for (int kt = 28; kt < 56; ++kt){
                        bf16x8 a = *(const bf16x8*)(aGc + (kt-16)*32);
                        acc = __builtin_amdgcn_mfma_f32_16x16x32_bf16(a, BL[kt*64 + l], acc, 0,0,0);
                    }
                } else if (kq == 2){
                    #pragma unroll 6
                    for (int kt = 56; kt < 80; ++kt){
                        bf16x8 a = *(const bf16x8*)(aGc + (kt-16)*32);
                        acc = __builtin_amdgcn_mfma_f32_16x16x32_bf16(a, BL[kt*64 + l], acc, 0,0,0);
                    }
                }
                #pragma unroll
                for (int r=0; r<4; ++r) sh.gem.Dp[kq][16*rt + 4*lk + r][lm] = acc[r];
            }
        }
        __syncthreads();

        // ---- LSTM pointwise ----
        int j2 = tid & 63, du = tid >> 6;
        int u = 4*b + du;
        float cNew = 0.f, hNew = 0.f, hKeep = 0.f, cOld = 0.f;
        bool active = false;
        if (tid < 256){
            float g4[4];
            #pragma unroll
            for (int g=0; g<4; ++g){
                int nl = 4*du + g;
                g4[g] = sh.gem.Dp[0][j2][nl] + sh.gem.Dp[1][j2][nl]
                      + sh.gem.Dp[2][j2][nl] + sh.gem.Dp[3][j2][nl] + p.bsum[16*b + nl];
            }
            float ig = sigm(g4[0]), fg = sigm(g4[1]), gg = tanhf(g4[2]), og = sigm(g4[3]);
            cOld = p.cW[j2*HID + u];
            cNew = fg*cOld + ig*gg;
            hNew = og*tanhf(cNew);
            active = (t < sh.gem.lensL[j2]);
            float hOld = hFIn[j2*HID + u];
            hKeep = active ? hNew : hOld;
            sh.gem.hS[j2][du] = hKeep;
        }
        __syncthreads();
        if (tid < 128){
            int jb = tid & 63, dp = tid >> 6;
            int u0 = 4*b + 2*dp;
            stgu((unsigned*)((short*)hbOut + jb*HID + u0),
                 pkbf(sh.gem.hS[jb][2*dp], sh.gem.hS[jb][2*dp+1]));
        }
        gbar_arrive(p.barCnt, bk);     // h(t+1) visible; private/external stores in shadow
        if (tid < 256){
            p.cW[j2*HID + u] = active ? cNew : cOld;
            hFOut[j2*HID + u] = hKeep;
            p.outH[((size_t)sh.gem.wLs[j2]*T + t)*HID + u] = active ? hNew : 0.f;
        }
        gbar_wait(p.barCnt, bk); bk++;
    }
}

extern "C" void kernel_launch(void* const* d_in, const int* in_sizes, int n_in,
                              void* d_out, int out_size, void* d_ws, size_t ws_size,
                              hipStream_t stream) {
    const float* img   = (const float*)d_in[0];
    const int*   sent  = (const int*)  d_in[1];
    const float* enc_h = (const float*)d_in[2];
    const float* enc_c = (const float*)d_in[3];
    const int*   lens  = (const int*)  d_in[4];
    const float* emb   = (const float*)d_in[5];
    const float* Wea   = (const float*)d_in[6];
    const float* bea   = (const float*)d_in[7];
    const float* Wda   = (const float*)d_in[8];
    const float* bda   = (const float*)d_in[9];
    const float* wfa   = (const float*)d_in[10];
    const float* bfa   = (const float*)d_in[11];
    const float* Wfb   = (const float*)d_in[12];
    const float* bfb   = (const float*)d_in[13];
    const float* Wih   = (const float*)d_in[14];
    const float* bih   = (const float*)d_in[15];
    const float* Whh   = (const float*)d_in[16];
    const float* bhh   = (const float*)d_in[17];

    float* outH = (float*)d_out;                       // [B,T,HID] f32
    float* outA = outH + (size_t)B*T*HID;              // [B,T,P]  f32

    char* wsb = (char*)d_ws;
    size_t off = 0;
    int* idxW  = (int*)(wsb + off); off += 256;
    int* rankW = (int*)(wsb + off); off += 256;
    int* nActW = (int*)(wsb + off); off += 1024;
    unsigned* barCnt = (unsigned*)(wsb + off); off += 131072;   // arr 64KB + gdone 4KB + rel 4KB (padded)
    __hip_bfloat16* att1w = (__hip_bfloat16*)(wsb + off); off += (size_t)B*P*ATT*2;       // 12.85MB
    __hip_bfloat16* img_s = (__hip_bfloat16*)(wsb + off); off += (size_t)B*P*ENC*2;       // 51.38MB
    __hip_bfloat16* emb_bf= (__hip_bfloat16*)(wsb + off); off += (size_t)10000*EMB*2;     // 10.24MB
    __hip_bfloat16* Wfrag = (__hip_bfloat16*)(wsb + off); off += (size_t)4*HID*KTOT*2;    // 29.36MB
    __hip_bfloat16* W2    = (__hip_bfloat16*)(wsb + off); off += (size_t)N2*HID*2;        // 5.24MB
    __hip_bfloat16* Wea_bf= (__hip_bfloat16*)(wsb + off); off += (size_t)ATT*ENC*2;       // 2.10MB (prologue-only)
    float* bsum  = (float*)(wsb + off); off += 4*HID*4;
    float* bias2 = (float*)(wsb + off); off += N2*4;
    float* hA    = (float*)(wsb + off); off += B*HID*4;
    float* hB    = (float*)(wsb + off); off += B*HID*4;
    float* cWs   = (float*)(wsb + off); off += B*HID*4;
    float* D2    = (float*)(wsb + off); off += (size_t)B*N2*4;
    __hip_bfloat16* gcR = (__hip_bfloat16*)(wsb + off); off += (size_t)T*B*ENC*2;         // 41.9MB rotating
    __hip_bfloat16* hbR = (__hip_bfloat16*)(wsb + off); off += (size_t)(T+1)*B*HID*2;     // 21.1MB rotating

    k_sort<<<1, 64, 0, stream>>>(lens, idxW, rankW, barCnt, nActW);
    k_init_hc<<<B, 256, 0, stream>>>(enc_h, enc_c, idxW, hA, cWs, hbR);
    k_cvt_wcat<<<57344, 256, 0, stream>>>(Wih, Whh, Wfrag);
    k_bsum<<<16, 256, 0, stream>>>(bih, bhh, bsum);
    k_cvt_w2<<<N2, 256, 0, stream>>>(Wda, bda, Wfb, bfb, W2, bias2);
    k_cvt_emb<<<20000, 256, 0, stream>>>(emb, emb_bf);
    k_cvt_wea<<<ATT, 256, 0, stream>>>(Wea, Wea_bf);
    k_cvt_img<<<dim3(P*ENC/256, B), 256, 0, stream>>>(img, idxW, img_s);
    k_att1m<<<dim3((B*P)/64, ATT/64), 256, 0, stream>>>(img_s, Wea_bf, bea, att1w);

    SP sp;
    sp.att1w = att1w; sp.img_s = img_s; sp.emb_bf = emb_bf; sp.Wfrag = Wfrag; sp.W2 = W2;
    sp.bsum = bsum; sp.bias2 = bias2; sp.wfa = wfa; sp.bfa = bfa;
    sp.sent = sent; sp.idx = idxW; sp.rank = rankW; sp.lens = lens; sp.nAct = nActW;
    sp.D2 = D2; sp.gcR = gcR; sp.hbR = hbR;
    sp.hF0 = hA; sp.hF1 = hB; sp.cW = cWs;
    sp.outH = outH; sp.outA = outA;
    sp.barCnt = barCnt;

    void* args[] = { &sp };
    hipLaunchCooperativeKernel(reinterpret_cast<void*>(k_scan), dim3(NBLK), dim3(NTHR),
                               args, 0, stream);
}

// Round 16
// 6977.305 us; speedup vs baseline: 1.0200x; 1.0200x over previous
//
#include <hip/hip_runtime.h>
#include <hip/hip_bf16.h>
#include <math.h>

#define B 64
#define T 160
#define P 196
#define ENC 2048
#define ATT 512
#define EMB 512
#define HID 1024
#define KTOT 3584   // EMB + ENC + HID
#define N2 2560     // ATT + ENC
#define KT4 112     // KTOT/32
#define NTHR 1024
#define NBLK 256
#define NGRP 16
#define GRPSZ (NBLK/NGRP)

// barrier word-offsets (unsigned words), 256B (64-word) stride per slot
#define ARR_W 0            // 256 arrival slots
#define GD_W  16384        // 16 group-done slots
#define REL_W 17408        // 16 release slots

typedef __attribute__((ext_vector_type(8))) short bf16x8;
typedef __attribute__((ext_vector_type(4))) float f32x4;
typedef float __attribute__((ext_vector_type(4))) vf4;

__device__ __forceinline__ float sigm(float x){ return 1.0f/(1.0f+__expf(-x)); }
__device__ __forceinline__ float bfu(short s){ return __uint_as_float(((unsigned)(unsigned short)s) << 16); }

// ---- MALL-coherent movement for cross-block data (volatile => sc0 sc1) ----
__device__ __forceinline__ float ldgf(const float* p){ return *(const volatile float*)p; }
__device__ __forceinline__ void stgf(float* p, float v){ *(volatile float*)p = v; }
__device__ __forceinline__ void stgu(unsigned* p, unsigned v){ *(volatile unsigned*)p = v; }
__device__ __forceinline__ unsigned pkbf(float a, float b){
    unsigned ua = (unsigned)__bfloat16_as_ushort(__float2bfloat16(a));
    unsigned ub = (unsigned)__bfloat16_as_ushort(__float2bfloat16(b));
    return ua | (ub << 16);
}

// ---- store-based grid barrier: parallel arrival stores + wave-swept detection ----
__device__ __forceinline__ void gbar_arrive(unsigned* bar, unsigned k){
    asm volatile("s_waitcnt vmcnt(0)" ::: "memory");   // data stores acked before arrival flag
    __syncthreads();
    if (threadIdx.x == 0)
        *(volatile unsigned*)(bar + ARR_W + (unsigned)blockIdx.x*64) = k + 1u;
}
__device__ __forceinline__ void gbar_wait(unsigned* bar, unsigned k){
    int b = blockIdx.x, tid = threadIdx.x;
    if (b < NGRP){
        if (tid < 64){
            // sweep my group's 16 arrival slots (members: m*16 + b)
            volatile unsigned* s = (volatile unsigned*)(bar + ARR_W + (unsigned)((tid & 15)*NGRP + b)*64);
            while (!__all(*s >= k + 1u)) __builtin_amdgcn_s_sleep(1);
            if (tid == 0) *(volatile unsigned*)(bar + GD_W + b*64) = k + 1u;
            // sweep all 16 group-done slots
            volatile unsigned* g = (volatile unsigned*)(bar + GD_W + (tid & 15)*64);
            while (!__all(*g >= k + 1u)) __builtin_amdgcn_s_sleep(1);
            if (tid == 0) *(volatile unsigned*)(bar + REL_W + b*64) = k + 1u;
        }
    } else {
        if (tid == 0){
            volatile unsigned* r = (volatile unsigned*)(bar + REL_W + (b & (NGRP-1))*64);
            while (*r < k + 1u) __builtin_amdgcn_s_sleep(1);
        }
    }
    __syncthreads();
    asm volatile("" ::: "memory");
}
__device__ __forceinline__ void gbar(unsigned* bar, unsigned k){
    gbar_arrive(bar, k);
    gbar_wait(bar, k);
}

// ---------- sort + nAct table ----------
__global__ void k_sort(const int* lens, int* idx, int* rank, unsigned* barCnt, int* nAct){
    __shared__ int L[B];
    int i = threadIdx.x;
    L[i] = lens[i];
    for (int s = i; s < 288; s += B){
        int wofs = (s < 256) ? (ARR_W + s*64)
                 : (s < 272) ? (GD_W + (s-256)*64)
                             : (REL_W + (s-272)*64);
        barCnt[wofs] = 0u;
    }
    __syncthreads();
    int li = L[i];
    int r = 0;
    for (int j = 0; j < B; ++j){
        int lj = L[j];
        if (lj > li || (lj == li && j < i)) r++;
    }
    rank[i] = r;
    idx[r] = i;
    for (int tt = i; tt < T; tt += B){
        int c = 0;
        for (int j = 0; j < B; ++j) c += (L[j] > tt) ? 1 : 0;
        nAct[tt] = c;
    }
}

// ---------- init h0/c0 (sorted) + bf16 copy into hbR slot 0 ----------
__global__ void k_init_hc(const float* enc_h, const float* enc_c, const int* idx,
                          float* h, float* c, __hip_bfloat16* hbR0){
    int j = blockIdx.x;
    int o = idx[j];
    for (int k = threadIdx.x; k < HID; k += blockDim.x){
        float hv = (k < 512) ? enc_h[o*512 + k] : enc_h[B*512 + o*512 + (k-512)];
        float cv = (k < 512) ? enc_c[o*512 + k] : enc_c[B*512 + o*512 + (k-512)];
        h[j*HID + k] = hv;
        c[j*HID + k] = cv;
        hbR0[j*HID + k] = __float2bfloat16(hv);
    }
}

// ---------- Wcat in per-strip MFMA-fragment order (once) ----------
__global__ void k_cvt_wcat(const float* Wih, const float* Whh, __hip_bfloat16* Wfrag){
    size_t i = (size_t)blockIdx.x*256 + threadIdx.x;
    int e = (int)(i & 7);
    size_t t2 = i >> 3;
    int lane = (int)(t2 & 63);
    size_t t3 = t2 >> 6;
    int kt = (int)(t3 % KT4);
    int strip = (int)(t3 / KT4);
    int n = strip*16 + (lane & 15);
    int r = (n & 3)*HID + (n >> 2);
    int k = kt*32 + (lane >> 4)*8 + e;
    float v = (k < EMB+ENC) ? Wih[(size_t)r*(EMB+ENC) + k]
                            : Whh[(size_t)r*HID + (k - EMB - ENC)];
    Wfrag[i] = __float2bfloat16(v);
}

__global__ void k_bsum(const float* bih, const float* bhh, float* bsum){
    int n = blockIdx.x*256 + threadIdx.x;
    int r = (n & 3)*HID + (n >> 2);
    bsum[n] = bih[r] + bhh[r];
}

__global__ void k_cvt_w2(const float* Wda, const float* bda, const float* Wfb, const float* bfb,
                         __hip_bfloat16* W2, float* bias2){
    int n = blockIdx.x;
    const float* src = (n < ATT) ? (Wda + (size_t)n*HID) : (Wfb + (size_t)(n-ATT)*HID);
    __hip_bfloat16* dst = W2 + (size_t)n*HID;
    for (int k = threadIdx.x; k < HID; k += 256) dst[k] = __float2bfloat16(src[k]);
    if (threadIdx.x == 0) bias2[n] = (n < ATT) ? bda[n] : bfb[n-ATT];
}

__global__ void k_cvt_emb(const float* emb, __hip_bfloat16* emb_bf){
    size_t i = (size_t)blockIdx.x*256 + threadIdx.x;
    emb_bf[i] = __float2bfloat16(emb[i]);
}

__global__ void k_cvt_wea(const float* Wea, __hip_bfloat16* Wea_bf){
    int n = blockIdx.x;
    for (int k = threadIdx.x; k < ENC; k += 256)
        Wea_bf[(size_t)n*ENC + k] = __float2bfloat16(Wea[(size_t)n*ENC + k]);
}

__global__ void k_cvt_img(const float* img, const int* idx, __hip_bfloat16* img_s){
    int j = blockIdx.y;
    int o = idx[j];
    size_t off = (size_t)blockIdx.x*256 + threadIdx.x;
    img_s[(size_t)j*P*ENC + off] = __float2bfloat16(img[(size_t)o*P*ENC + off]);
}

// ---------- att1 (once, MFMA) ----------
__global__ __launch_bounds__(256) void k_att1m(const __hip_bfloat16* img_s, const __hip_bfloat16* Wea_bf,
                                               const float* bea, __hip_bfloat16* att1w){
    int m0 = blockIdx.x * 64, n0 = blockIdx.y * 64;
    int tid = threadIdx.x, w = tid >> 6, l = tid & 63, lm = l & 15, lk = l >> 4;
    const short* ap = (const short*)img_s + (size_t)(m0 + 16*w + lm)*ENC + 8*lk;
    const short* bp = (const short*)Wea_bf + (size_t)(n0 + lm)*ENC + 8*lk;
    f32x4 acc[4];
    #pragma unroll
    for (int nt=0; nt<4; ++nt) acc[nt] = (f32x4){0.f,0.f,0.f,0.f};
    #pragma unroll 4
    for (int kt = 0; kt < ENC/32; ++kt){
        bf16x8 a = *(const bf16x8*)(ap + kt*32);
        #pragma unroll
        for (int nt=0; nt<4; ++nt){
            bf16x8 bb = *(const bf16x8*)(bp + (size_t)nt*16*ENC + kt*32);
            acc[nt] = __builtin_amdgcn_mfma_f32_16x16x32_bf16(a, bb, acc[nt], 0,0,0);
        }
    }
    #pragma unroll
    for (int nt=0; nt<4; ++nt){
        int n = n0 + nt*16 + lm;
        float bv = bea[n];
        #pragma unroll
        for (int r=0; r<4; ++r){
            int m = m0 + 16*w + 4*lk + r;
            att1w[(size_t)m*ATT + n] = __float2bfloat16(acc[nt][r] + bv);
        }
    }
}

// ---------- persistent cooperative scan ----------
struct SP {
    const __hip_bfloat16 *att1w, *img_s, *emb_bf, *Wfrag, *W2;
    const float *bsum, *bias2, *wfa, *bfa;
    const int *sent, *idx, *rank, *lens, *nAct;
    float *D2;
    __hip_bfloat16 *gcR, *hbR;     // rotating: gcR[t], hbR[t] (hbR has T+1 slots)
    float *hF0, *hF1, *cW;
    float *outH, *outA;
    unsigned *barCnt;
};

__global__ __launch_bounds__(1024, 4) void k_scan(SP p){
    __shared__ short WcatL[KT4*64*8];          // 114,688 B, fragment-ordered
    __shared__ union {
        struct { float Dp[4][64][17]; float hS[64][4]; int tokL[64], lensL[64], wLs[64]; } gem;
        struct { float att2L[512]; float wfaL[512]; float red[1024]; float aL[208]; float ctxP[8][512]; } p23;
    } sh;

    int b = blockIdx.x, tid = threadIdx.x;
    int w = tid >> 6, l = tid & 63, lm = l & 15, lk = l >> 4;
    unsigned bk = 0;

    // one-time LDS fill (straight copy, frag order)
    {
        const bf16x8* src = (const bf16x8*)((const short*)p.Wfrag + (size_t)b*KT4*64*8);
        bf16x8* dst = (bf16x8*)WcatL;
        #pragma unroll
        for (int i = 0; i < KT4*64/NTHR; ++i) dst[tid + i*NTHR] = src[tid + i*NTHR];
    }
    __syncthreads();

    float bfa0 = p.bfa[0];

    for (int t = 0; t < T; ++t){
        const __hip_bfloat16* hbIn = p.hbR + (size_t)t*B*HID;
        __hip_bfloat16*       hbOut = p.hbR + (size_t)(t+1)*B*HID;
        const __hip_bfloat16* gcT  = p.gcR + (size_t)t*B*ENC;
        const float* hFIn = (t & 1) ? p.hF1 : p.hF0;
        float*       hFOut = (t & 1) ? p.hF0 : p.hF1;
        int nAct = p.nAct[t];

        // ---- P1: D2[64][2560] = h_bf @ W2^T + bias2 ; blocks < 160, 4-way K-split ----
        if (b < N2/16){
            int n0 = b*16;
            int rt = w & 3, kq = w >> 2;
            if (16*rt < nAct){
                const short* ap = (const short*)hbIn + (size_t)(16*rt + lm)*HID + kq*256 + 8*lk;
                const short* bp = (const short*)p.W2 + (size_t)(n0 + lm)*HID + kq*256 + 8*lk;
                f32x4 acc = {0.f,0.f,0.f,0.f};
                #pragma unroll
                for (int kt = 0; kt < 8; ++kt){
                    bf16x8 a = *(const bf16x8*)(ap + kt*32);
                    bf16x8 bb = *(const bf16x8*)(bp + kt*32);
                    acc = __builtin_amdgcn_mfma_f32_16x16x32_bf16(a, bb, acc, 0,0,0);
                }
                #pragma unroll
                for (int r=0; r<4; ++r) sh.gem.Dp[kq][16*rt + 4*lk + r][lm] = acc[r];
            }
            __syncthreads();
            int m = tid >> 4, nl = tid & 15;
            if (m < nAct){
                stgf(&p.D2[m*N2 + n0 + nl],
                     sh.gem.Dp[0][m][nl] + sh.gem.Dp[1][m][nl]
                   + sh.gem.Dp[2][m][nl] + sh.gem.Dp[3][m][nl] + p.bias2[n0 + nl]);
            }
        }
        gbar(p.barCnt, bk); bk++;

        // ---- P23: e + softmax + context + gc ; block = (j=b&63, q=b>>6) ----
        int jj = b & 63, qq = b >> 6;
        int oo = p.idx[jj], wjj = p.rank[jj], ljj = p.lens[oo];
        {
            if (t < ljj){
                if (tid < 512){
                    sh.p23.att2L[tid] = ldgf(&p.D2[jj*N2 + tid]);
                    sh.p23.wfaL[tid]  = p.wfa[tid];
                }
                __syncthreads();

                int pp = tid & 255, ah = tid >> 8;
                float acc = 0.f;
                if (pp < P){
                    const short* ar = (const short*)p.att1w + (size_t)(jj*P + pp)*ATT + ah*128;
                    #pragma unroll 8
                    for (int k8 = 0; k8 < 16; ++k8){
                        bf16x8 v = *(const bf16x8*)(ar + k8*8);
                        #pragma unroll
                        for (int z=0; z<8; ++z){
                            int a = ah*128 + k8*8 + z;
                            acc += fmaxf(bfu(v[z]) + sh.p23.att2L[a], 0.f) * sh.p23.wfaL[a];
                        }
                    }
                }
                sh.p23.red[tid] = acc;
                __syncthreads();
                float e = -1e30f;
                if (tid < P) e = sh.p23.red[tid] + sh.p23.red[tid+256] + sh.p23.red[tid+512] + sh.p23.red[tid+768] + bfa0;
                __syncthreads();
                sh.p23.red[tid] = (tid < P) ? e : -1e30f;
                __syncthreads();
                for (int s = 512; s > 0; s >>= 1){
                    if (tid < s) sh.p23.red[tid] = fmaxf(sh.p23.red[tid], sh.p23.red[tid+s]);
                    __syncthreads();
                }
                float m = sh.p23.red[0];
                __syncthreads();
                float ex = (tid < P) ? __expf(e - m) : 0.f;
                sh.p23.red[tid] = ex;
                __syncthreads();
                for (int s = 512; s > 0; s >>= 1){
                    if (tid < s) sh.p23.red[tid] += sh.p23.red[tid+s];
                    __syncthreads();
                }
                float ssum = sh.p23.red[0];
                if (tid < P) sh.p23.aL[tid] = ex / ssum;
                if (tid >= P && tid < 208) sh.p23.aL[tid] = 0.f;
                __syncthreads();

                const short* ib = (const short*)p.img_s + (size_t)jj*P*ENC + qq*512 + l*8;
                float a8[8];
                #pragma unroll
                for (int z=0; z<8; ++z) a8[z] = 0.f;
                #pragma unroll 4
                for (int i = 0; i < 13; ++i){
                    int pp2 = w + 16*i;
                    int pr = (pp2 < P) ? pp2 : 0;
                    bf16x8 v = *(const bf16x8*)(ib + (size_t)pr*ENC);
                    float al = sh.p23.aL[pp2];
                    #pragma unroll
                    for (int z=0; z<8; ++z) a8[z] += al * bfu(v[z]);
                }
                if (w < 8){
                    #pragma unroll
                    for (int z=0; z<8; ++z) sh.p23.ctxP[w][l*8+z] = a8[z];
                }
                __syncthreads();
                if (w >= 8){
                    #pragma unroll
                    for (int z=0; z<8; ++z) sh.p23.ctxP[w-8][l*8+z] += a8[z];
                }
                __syncthreads();
                if (tid < 256){
                    int d0 = 2*tid;
                    float c0 = 0.f, c1 = 0.f;
                    #pragma unroll
                    for (int r=0; r<8; ++r){ c0 += sh.p23.ctxP[r][d0]; c1 += sh.p23.ctxP[r][d0+1]; }
                    int eg0 = qq*512 + d0;
                    float g0 = sigm(ldgf(&p.D2[jj*N2 + ATT + eg0]));
                    float g1 = sigm(ldgf(&p.D2[jj*N2 + ATT + eg0 + 1]));
                    stgu((unsigned*)((short*)gcT + jj*ENC + eg0), pkbf(g0*c0, g1*c1));
                }
            }
        }
        gbar_arrive(p.barCnt, bk);     // gc visible; do independent work in the wait shadow

        // outA write (external-only) in barrier shadow
        if (qq == 0 && tid < P){
            float av = (t < ljj) ? sh.p23.aL[tid] : 0.f;
            p.outA[((size_t)(wjj*T + t))*P + tid] = av;
        }
        __syncthreads();               // close p23 LDS usage before gem reuse

        // ---- P4 prelude + non-gc MFMA (emb + h segments) in barrier shadow ----
        if (tid < 64){
            int o = p.idx[tid];
            sh.gem.tokL[tid] = p.sent[o*T + t];
            sh.gem.lensL[tid] = p.lens[o];
            sh.gem.wLs[tid] = p.rank[tid];
        }
        __syncthreads();
        {
            int rt = w & 3, kq = w >> 2;
            bool act = (16*rt < nAct);
            int mrow = 16*rt + lm;
            f32x4 acc = {0.f,0.f,0.f,0.f};
            const short* aEmb = 0; const short* aGc = 0; const short* aH = 0;
            const bf16x8* BL = (const bf16x8*)WcatL;
            if (act){
                int tok = sh.gem.tokL[mrow];
                aEmb = (const short*)p.emb_bf + (size_t)tok*EMB + 8*lk;
                aGc  = (const short*)gcT + (size_t)mrow*ENC + 8*lk;
                aH   = (const short*)hbIn + (size_t)mrow*HID + 8*lk;
                if (kq == 0){
                    #pragma unroll 8
                    for (int kt = 0; kt < 16; ++kt){
                        bf16x8 a = *(const bf16x8*)(aEmb + kt*32);
                        acc = __builtin_amdgcn_mfma_f32_16x16x32_bf16(a, BL[kt*64 + l], acc, 0,0,0);
                    }
                } else if (kq == 2){
                    #pragma unroll
                    for (int kt = 80; kt < 84; ++kt){
                        bf16x8 a = *(const bf16x8*)(aH + (kt-80)*32);
                        acc = __builtin_amdgcn_mfma_f32_16x16x32_bf16(a, BL[kt*64 + l], acc, 0,0,0);
                    }
                } else if (kq == 3){
                    #pragma unroll 7
                    for (int kt = 84; kt < 112; ++kt){
                        bf16x8 a = *(const bf16x8*)(aH + (kt-80)*32);
                        acc = __builtin_amdgcn_mfma_f32_16x16x32_bf16(a, BL[kt*64 + l], acc, 0,0,0);
                    }
                }
            }
            gbar_wait(p.barCnt, bk); bk++;    // gc now ready

            if (act){
                if (kq == 0){
                    #pragma unroll 6
                    for (int kt = 16; kt < 28; ++kt){
                        bf16x8 a = *(const bf16x8*)(aGc + (kt-16)*32);
                        acc = __builtin_amdgcn_mfma_f32_16x16x32_bf16(a, BL[kt*64 + l], acc, 0,0,0);
                    }
                } else if (kq == 1){
                    #pragma unroll 7
                    for (int kt = 28; kt < 56; ++kt){
                        bf16x8 a = *(const bf16x8*)(aGc + (kt-16)*32);
                        acc = __builtin_amdgcn_mfma_f32_16x16x32_bf16(a, BL[kt*64 + l], acc, 0,0,0);
                    }
                } else if (kq == 2){
                    #pragma unroll 6
                    for (int kt = 56; kt < 80; ++kt){
                        bf16x8 a = *(const bf16x8*)(aGc + (kt-16)*32);
                        acc = __builtin_amdgcn_mfma_f32_16x16x32_bf16(a, BL[kt*64 + l], acc, 0,0,0);
                    }
                }
                #pragma unroll
                for (int r=0; r<4; ++r) sh.gem.Dp[kq][16*rt + 4*lk + r][lm] = acc[r];
            }
        }
        __syncthreads();

        // ---- LSTM pointwise ----
        int j2 = tid & 63, du = tid >> 6;
        int u = 4*b + du;
        float cNew = 0.f, hNew = 0.f, hKeep = 0.f, cOld = 0.f;
        bool active = false;
        if (tid < 256){
            float g4[4];
            #pragma unroll
            for (int g=0; g<4; ++g){
                int nl = 4*du + g;
                g4[g] = sh.gem.Dp[0][j2][nl] + sh.gem.Dp[1][j2][nl]
                      + sh.gem.Dp[2][j2][nl] + sh.gem.Dp[3][j2][nl] + p.bsum[16*b + nl];
            }
            float ig = sigm(g4[0]), fg = sigm(g4[1]), gg = tanhf(g4[2]), og = sigm(g4[3]);
            cOld = p.cW[j2*HID + u];
            cNew = fg*cOld + ig*gg;
            hNew = og*tanhf(cNew);
            active = (t < sh.gem.lensL[j2]);
            float hOld = hFIn[j2*HID + u];
            hKeep = active ? hNew : hOld;
            sh.gem.hS[j2][du] = hKeep;
        }
        __syncthreads();
        if (tid < 128){
            int jb = tid & 63, dp = tid >> 6;
            int u0 = 4*b + 2*dp;
            stgu((unsigned*)((short*)hbOut + jb*HID + u0),
                 pkbf(sh.gem.hS[jb][2*dp], sh.gem.hS[jb][2*dp+1]));
        }
        gbar_arrive(p.barCnt, bk);     // h(t+1) visible; private/external stores in shadow
        if (tid < 256){
            p.cW[j2*HID + u] = active ? cNew : cOld;
            hFOut[j2*HID + u] = hKeep;
            p.outH[((size_t)sh.gem.wLs[j2]*T + t)*HID + u] = active ? hNew : 0.f;
        }
        gbar_wait(p.barCnt, bk); bk++;
    }
}

extern "C" void kernel_launch(void* const* d_in, const int* in_sizes, int n_in,
                              void* d_out, int out_size, void* d_ws, size_t ws_size,
                              hipStream_t stream) {
    const float* img   = (const float*)d_in[0];
    const int*   sent  = (const int*)  d_in[1];
    const float* enc_h = (const float*)d_in[2];
    const float* enc_c = (const float*)d_in[3];
    const int*   lens  = (const int*)  d_in[4];
    const float* emb   = (const float*)d_in[5];
    const float* Wea   = (const float*)d_in[6];
    const float* bea   = (const float*)d_in[7];
    const float* Wda   = (const float*)d_in[8];
    const float* bda   = (const float*)d_in[9];
    const float* wfa   = (const float*)d_in[10];
    const float* bfa   = (const float*)d_in[11];
    const float* Wfb   = (const float*)d_in[12];
    const float* bfb   = (const float*)d_in[13];
    const float* Wih   = (const float*)d_in[14];
    const float* bih   = (const float*)d_in[15];
    const float* Whh   = (const float*)d_in[16];
    const float* bhh   = (const float*)d_in[17];

    float* outH = (float*)d_out;                       // [B,T,HID] f32
    float* outA = outH + (size_t)B*T*HID;              // [B,T,P]  f32

    char* wsb = (char*)d_ws;
    size_t off = 0;
    int* idxW  = (int*)(wsb + off); off += 256;
    int* rankW = (int*)(wsb + off); off += 256;
    int* nActW = (int*)(wsb + off); off += 1024;
    unsigned* barCnt = (unsigned*)(wsb + off); off += 131072;   // arr 64KB + gdone 4KB + rel 4KB (padded)
    __hip_bfloat16* att1w = (__hip_bfloat16*)(wsb + off); off += (size_t)B*P*ATT*2;       // 12.85MB
    __hip_bfloat16* img_s = (__hip_bfloat16*)(wsb + off); off += (size_t)B*P*ENC*2;       // 51.38MB
    __hip_bfloat16* emb_bf= (__hip_bfloat16*)(wsb + off); off += (size_t)10000*EMB*2;     // 10.24MB
    __hip_bfloat16* Wfrag = (__hip_bfloat16*)(wsb + off); off += (size_t)4*HID*KTOT*2;    // 29.36MB
    __hip_bfloat16* W2    = (__hip_bfloat16*)(wsb + off); off += (size_t)N2*HID*2;        // 5.24MB
    __hip_bfloat16* Wea_bf= (__hip_bfloat16*)(wsb + off); off += (size_t)ATT*ENC*2;       // 2.10MB (prologue-only)
    float* bsum  = (float*)(wsb + off); off += 4*HID*4;
    float* bias2 = (float*)(wsb + off); off += N2*4;
    float* hA    = (float*)(wsb + off); off += B*HID*4;
    float* hB    = (float*)(wsb + off); off += B*HID*4;
    float* cWs   = (float*)(wsb + off); off += B*HID*4;
    float* D2    = (float*)(wsb + off); off += (size_t)B*N2*4;
    __hip_bfloat16* gcR = (__hip_bfloat16*)(wsb + off); off += (size_t)T*B*ENC*2;         // 41.9MB rotating
    __hip_bfloat16* hbR = (__hip_bfloat16*)(wsb + off); off += (size_t)(T+1)*B*HID*2;     // 21.1MB rotating

    k_sort<<<1, 64, 0, stream>>>(lens, idxW, rankW, barCnt, nActW);
    k_init_hc<<<B, 256, 0, stream>>>(enc_h, enc_c, idxW, hA, cWs, hbR);
    k_cvt_wcat<<<57344, 256, 0, stream>>>(Wih, Whh, Wfrag);
    k_bsum<<<16, 256, 0, stream>>>(bih, bhh, bsum);
    k_cvt_w2<<<N2, 256, 0, stream>>>(Wda, bda, Wfb, bfb, W2, bias2);
    k_cvt_emb<<<20000, 256, 0, stream>>>(emb, emb_bf);
    k_cvt_wea<<<ATT, 256, 0, stream>>>(Wea, Wea_bf);
    k_cvt_img<<<dim3(P*ENC/256, B), 256, 0, stream>>>(img, idxW, img_s);
    k_att1m<<<dim3((B*P)/64, ATT/64), 256, 0, stream>>>(img_s, Wea_bf, bea, att1w);

    SP sp;
    sp.att1w = att1w; sp.img_s = img_s; sp.emb_bf = emb_bf; sp.Wfrag = Wfrag; sp.W2 = W2;
    sp.bsum = bsum; sp.bias2 = bias2; sp.wfa = wfa; sp.bfa = bfa;
    sp.sent = sent; sp.idx = idxW; sp.rank = rankW; sp.lens = lens; sp.nAct = nActW;
    sp.D2 = D2; sp.gcR = gcR; sp.hbR = hbR;
    sp.hF0 = hA; sp.hF1 = hB; sp.cW = cWs;
    sp.outH = outH; sp.outA = outA;
    sp.barCnt = barCnt;

    void* args[] = { &sp };
    hipLaunchCooperativeKernel(reinterpret_cast<void*>(k_scan), dim3(NBLK), dim3(NTHR),
                               args, 0, stream);
}

// Round 17
// 6884.296 us; speedup vs baseline: 1.0338x; 1.0135x over previous
//
#include <hip/hip_runtime.h>
#include <hip/hip_bf16.h>
#include <math.h>

#define B 64
#define T 160
#define P 196
#define ENC 2048
#define ATT 512
#define EMB 512
#define HID 1024
#define KTOT 3584   // EMB + ENC + HID
#define N2 2560     // ATT + ENC
#define KT4 112     // KTOT/32
#define NTHR 1024
#define NBLK 256
#define NGRP 16
#define GRPSZ (NBLK/NGRP)

// barrier word-offsets (unsigned words), 256B (64-word) stride per slot
#define ARR_W 0            // 256 arrival slots
#define GD_W  16384        // 16 group-done slots
#define REL_W 17408        // 16 release slots

typedef __attribute__((ext_vector_type(8))) short bf16x8;
typedef __attribute__((ext_vector_type(4))) float f32x4;
typedef __attribute__((ext_vector_type(2))) float f32x2;

__device__ __forceinline__ float sigm(float x){ return 1.0f/(1.0f+__expf(-x)); }
__device__ __forceinline__ float bfu(short s){ return __uint_as_float(((unsigned)(unsigned short)s) << 16); }
__device__ __forceinline__ short f2bf(float x){ __hip_bfloat16 h = __float2bfloat16(x); return *(short*)&h; }

// ---- fp8 e4m3fn decode (hot path) ----
#if __has_builtin(__builtin_amdgcn_cvt_pk_f32_fp8)
#define FP8_DEC2(w, sel) __builtin_amdgcn_cvt_pk_f32_fp8((int)(w), (sel))
#else
__device__ __forceinline__ float fp8dec1(unsigned b){
    unsigned s = b >> 7, e = (b >> 3) & 15, m = b & 7;
    float v = e ? __uint_as_float(((e + 120u) << 23) | (m << 20)) : (float)(int)m * 0.001953125f;
    return s ? -v : v;
}
__device__ __forceinline__ f32x2 FP8_DEC2(unsigned w, int sel){
    unsigned h = sel ? (w >> 16) : (w & 0xFFFFu);
    f32x2 r; r.x = fp8dec1(h & 0xFF); r.y = fp8dec1(h >> 8);
    return r;
}
#endif

// ---- fp8 e4m3fn encode (prologue only, manual RNE) ----
__device__ __forceinline__ unsigned char fp8enc(float x){
    unsigned bits = __float_as_uint(x);
    unsigned s = (bits >> 31) << 7;
    unsigned abits = bits & 0x7FFFFFFFu;
    float a = __uint_as_float(abits);
    if (a >= 448.f) return (unsigned char)(s | 0x7E);          // clamp to max
    if (a < 0.0009765625f) return (unsigned char)s;            // < 2^-10 -> 0
    int E = (int)(abits >> 23) - 127;
    if (E < -6){                                               // subnormal target
        int q = (int)rintf(a * 512.0f);                        // 0..8
        if (q >= 8) return (unsigned char)(s | 0x08);
        return (unsigned char)(s | q);
    }
    unsigned m23 = abits & 0x7FFFFFu;
    unsigned r = (m23 + 0x7FFFFu + ((m23 >> 20) & 1u)) >> 20;  // RNE to 3 bits
    if (r >= 8){ r = 0; E++; }
    if (E > 8 || (E == 8 && r > 6)) return (unsigned char)(s | 0x7E);
    return (unsigned char)(s | ((unsigned)(E + 7) << 3) | r);
}

// ---- MALL-coherent movement for cross-block data (volatile => sc0 sc1) ----
__device__ __forceinline__ float ldgf(const float* p){ return *(const volatile float*)p; }
__device__ __forceinline__ void stgf(float* p, float v){ *(volatile float*)p = v; }
__device__ __forceinline__ void stgu(unsigned* p, unsigned v){ *(volatile unsigned*)p = v; }
__device__ __forceinline__ unsigned pkbf(float a, float b){
    unsigned ua = (unsigned)__bfloat16_as_ushort(__float2bfloat16(a));
    unsigned ub = (unsigned)__bfloat16_as_ushort(__float2bfloat16(b));
    return ua | (ub << 16);
}

// ---- store-based grid barrier: parallel arrival stores + wave-swept detection ----
__device__ __forceinline__ void gbar_arrive(unsigned* bar, unsigned k){
    asm volatile("s_waitcnt vmcnt(0)" ::: "memory");
    __syncthreads();
    if (threadIdx.x == 0)
        *(volatile unsigned*)(bar + ARR_W + (unsigned)blockIdx.x*64) = k + 1u;
}
__device__ __forceinline__ void gbar_wait(unsigned* bar, unsigned k){
    int b = blockIdx.x, tid = threadIdx.x;
    if (b < NGRP){
        if (tid < 64){
            volatile unsigned* s = (volatile unsigned*)(bar + ARR_W + (unsigned)((tid & 15)*NGRP + b)*64);
            while (!__all(*s >= k + 1u)) __builtin_amdgcn_s_sleep(1);
            if (tid == 0) *(volatile unsigned*)(bar + GD_W + b*64) = k + 1u;
            volatile unsigned* g = (volatile unsigned*)(bar + GD_W + (tid & 15)*64);
            while (!__all(*g >= k + 1u)) __builtin_amdgcn_s_sleep(1);
            if (tid == 0) *(volatile unsigned*)(bar + REL_W + b*64) = k + 1u;
        }
    } else {
        if (tid == 0){
            volatile unsigned* r = (volatile unsigned*)(bar + REL_W + (b & (NGRP-1))*64);
            while (*r < k + 1u) __builtin_amdgcn_s_sleep(1);
        }
    }
    __syncthreads();
    asm volatile("" ::: "memory");
}
__device__ __forceinline__ void gbar(unsigned* bar, unsigned k){
    gbar_arrive(bar, k);
    gbar_wait(bar, k);
}

// ---------- sort + nAct table ----------
__global__ void k_sort(const int* lens, int* idx, int* rank, unsigned* barCnt, int* nAct){
    __shared__ int L[B];
    int i = threadIdx.x;
    L[i] = lens[i];
    for (int s = i; s < 288; s += B){
        int wofs = (s < 256) ? (ARR_W + s*64)
                 : (s < 272) ? (GD_W + (s-256)*64)
                             : (REL_W + (s-272)*64);
        barCnt[wofs] = 0u;
    }
    __syncthreads();
    int li = L[i];
    int r = 0;
    for (int j = 0; j < B; ++j){
        int lj = L[j];
        if (lj > li || (lj == li && j < i)) r++;
    }
    rank[i] = r;
    idx[r] = i;
    for (int tt = i; tt < T; tt += B){
        int c = 0;
        for (int j = 0; j < B; ++j) c += (L[j] > tt) ? 1 : 0;
        nAct[tt] = c;
    }
}

// ---------- init h0/c0 (sorted) + bf16 copy into hbR slot 0 ----------
__global__ void k_init_hc(const float* enc_h, const float* enc_c, const int* idx,
                          float* h, float* c, __hip_bfloat16* hbR0){
    int j = blockIdx.x;
    int o = idx[j];
    for (int k = threadIdx.x; k < HID; k += blockDim.x){
        float hv = (k < 512) ? enc_h[o*512 + k] : enc_h[B*512 + o*512 + (k-512)];
        float cv = (k < 512) ? enc_c[o*512 + k] : enc_c[B*512 + o*512 + (k-512)];
        h[j*HID + k] = hv;
        c[j*HID + k] = cv;
        hbR0[j*HID + k] = __float2bfloat16(hv);
    }
}

// ---------- Wcat in per-strip MFMA-fragment order (once) ----------
__global__ void k_cvt_wcat(const float* Wih, const float* Whh, __hip_bfloat16* Wfrag){
    size_t i = (size_t)blockIdx.x*256 + threadIdx.x;
    int e = (int)(i & 7);
    size_t t2 = i >> 3;
    int lane = (int)(t2 & 63);
    size_t t3 = t2 >> 6;
    int kt = (int)(t3 % KT4);
    int strip = (int)(t3 / KT4);
    int n = strip*16 + (lane & 15);
    int r = (n & 3)*HID + (n >> 2);
    int k = kt*32 + (lane >> 4)*8 + e;
    float v = (k < EMB+ENC) ? Wih[(size_t)r*(EMB+ENC) + k]
                            : Whh[(size_t)r*HID + (k - EMB - ENC)];
    Wfrag[i] = __float2bfloat16(v);
}

__global__ void k_bsum(const float* bih, const float* bhh, float* bsum){
    int n = blockIdx.x*256 + threadIdx.x;
    int r = (n & 3)*HID + (n >> 2);
    bsum[n] = bih[r] + bhh[r];
}

__global__ void k_cvt_w2(const float* Wda, const float* bda, const float* Wfb, const float* bfb,
                         __hip_bfloat16* W2, float* bias2){
    int n = blockIdx.x;
    const float* src = (n < ATT) ? (Wda + (size_t)n*HID) : (Wfb + (size_t)(n-ATT)*HID);
    __hip_bfloat16* dst = W2 + (size_t)n*HID;
    for (int k = threadIdx.x; k < HID; k += 256) dst[k] = __float2bfloat16(src[k]);
    if (threadIdx.x == 0) bias2[n] = (n < ATT) ? bda[n] : bfb[n-ATT];
}

__global__ void k_cvt_emb(const float* emb, __hip_bfloat16* emb_bf){
    size_t i = (size_t)blockIdx.x*256 + threadIdx.x;
    emb_bf[i] = __float2bfloat16(emb[i]);
}

__global__ void k_cvt_wea(const float* Wea, __hip_bfloat16* Wea_bf){
    int n = blockIdx.x;
    for (int k = threadIdx.x; k < ENC; k += 256)
        Wea_bf[(size_t)n*ENC + k] = __float2bfloat16(Wea[(size_t)n*ENC + k]);
}

// img fp32 -> fp8 e4m3 (sorted order)
__global__ void k_cvt_img8(const float* img, const int* idx, unsigned char* img8){
    int j = blockIdx.y;
    int o = idx[j];
    size_t off = (size_t)blockIdx.x*256 + threadIdx.x;
    img8[(size_t)j*P*ENC + off] = fp8enc(img[(size_t)o*P*ENC + off]);
}

// ---------- att1 (once, MFMA): A from fp32 img (gather+cvt), B = Wea_bf ----------
__global__ __launch_bounds__(256) void k_att1m(const float* img, const int* idx,
                                               const __hip_bfloat16* Wea_bf,
                                               const float* bea, __hip_bfloat16* att1w){
    int m0 = blockIdx.x * 64, n0 = blockIdx.y * 64;
    int tid = threadIdx.x, w = tid >> 6, l = tid & 63, lm = l & 15, lk = l >> 4;
    int g = m0 + 16*w + lm;
    int j = g / P, pp2 = g - j*P;
    int o = idx[j];
    const float* af = img + ((size_t)o*P + pp2)*ENC + 8*lk;
    const short* bp = (const short*)Wea_bf + (size_t)(n0 + lm)*ENC + 8*lk;
    f32x4 acc[4];
    #pragma unroll
    for (int nt=0; nt<4; ++nt) acc[nt] = (f32x4){0.f,0.f,0.f,0.f};
    #pragma unroll 4
    for (int kt = 0; kt < ENC/32; ++kt){
        float4 f0 = *(const float4*)(af + kt*32);
        float4 f1 = *(const float4*)(af + kt*32 + 4);
        bf16x8 a;
        a[0]=f2bf(f0.x); a[1]=f2bf(f0.y); a[2]=f2bf(f0.z); a[3]=f2bf(f0.w);
        a[4]=f2bf(f1.x); a[5]=f2bf(f1.y); a[6]=f2bf(f1.z); a[7]=f2bf(f1.w);
        #pragma unroll
        for (int nt=0; nt<4; ++nt){
            bf16x8 bb = *(const bf16x8*)(bp + (size_t)nt*16*ENC + kt*32);
            acc[nt] = __builtin_amdgcn_mfma_f32_16x16x32_bf16(a, bb, acc[nt], 0,0,0);
        }
    }
    #pragma unroll
    for (int nt=0; nt<4; ++nt){
        int n = n0 + nt*16 + lm;
        float bv = bea[n];
        #pragma unroll
        for (int r=0; r<4; ++r){
            int m = m0 + 16*w + 4*lk + r;
            att1w[(size_t)m*ATT + n] = __float2bfloat16(acc[nt][r] + bv);
        }
    }
}

// ---------- persistent cooperative scan ----------
struct SP {
    const __hip_bfloat16 *att1w, *emb_bf, *Wfrag, *W2;
    const unsigned char *img8;
    const float *bsum, *bias2, *wfa, *bfa;
    const int *sent, *idx, *rank, *lens, *nAct;
    float *D2;
    __hip_bfloat16 *gcR, *hbR;     // rotating: gcR[t], hbR[t] (hbR has T+1 slots)
    float *hF0, *hF1, *cW;
    float *outH, *outA;
    unsigned *barCnt;
};

__global__ __launch_bounds__(1024, 4) void k_scan(SP p){
    __shared__ short WcatL[KT4*64*8];          // 114,688 B, fragment-ordered
    __shared__ union {
        struct { float Dp[4][64][17]; float hS[64][4]; int tokL[64], lensL[64], wLs[64]; } gem;
        struct { float att2L[512]; float wfaL[512]; float red[1024]; float aL[208]; float ctxP[8][512]; } p23;
    } sh;

    int b = blockIdx.x, tid = threadIdx.x;
    int w = tid >> 6, l = tid & 63, lm = l & 15, lk = l >> 4;
    unsigned bk = 0;

    // one-time LDS fill (straight copy, frag order)
    {
        const bf16x8* src = (const bf16x8*)((const short*)p.Wfrag + (size_t)b*KT4*64*8);
        bf16x8* dst = (bf16x8*)WcatL;
        #pragma unroll
        for (int i = 0; i < KT4*64/NTHR; ++i) dst[tid + i*NTHR] = src[tid + i*NTHR];
    }
    __syncthreads();

    float bfa0 = p.bfa[0];

    for (int t = 0; t < T; ++t){
        const __hip_bfloat16* hbIn = p.hbR + (size_t)t*B*HID;
        __hip_bfloat16*       hbOut = p.hbR + (size_t)(t+1)*B*HID;
        const __hip_bfloat16* gcT  = p.gcR + (size_t)t*B*ENC;
        const float* hFIn = (t & 1) ? p.hF1 : p.hF0;
        float*       hFOut = (t & 1) ? p.hF0 : p.hF1;
        int nAct = p.nAct[t];

        // ---- P1: D2[64][2560] = h_bf @ W2^T + bias2 ; blocks < 160, 4-way K-split ----
        if (b < N2/16){
            int n0 = b*16;
            int rt = w & 3, kq = w >> 2;
            if (16*rt < nAct){
                const short* ap = (const short*)hbIn + (size_t)(16*rt + lm)*HID + kq*256 + 8*lk;
                const short* bp = (const short*)p.W2 + (size_t)(n0 + lm)*HID + kq*256 + 8*lk;
                f32x4 acc = {0.f,0.f,0.f,0.f};
                #pragma unroll
                for (int kt = 0; kt < 8; ++kt){
                    bf16x8 a = *(const bf16x8*)(ap + kt*32);
                    bf16x8 bb = *(const bf16x8*)(bp + kt*32);
                    acc = __builtin_amdgcn_mfma_f32_16x16x32_bf16(a, bb, acc, 0,0,0);
                }
                #pragma unroll
                for (int r=0; r<4; ++r) sh.gem.Dp[kq][16*rt + 4*lk + r][lm] = acc[r];
            }
            __syncthreads();
            int m = tid >> 4, nl = tid & 15;
            if (m < nAct){
                stgf(&p.D2[m*N2 + n0 + nl],
                     sh.gem.Dp[0][m][nl] + sh.gem.Dp[1][m][nl]
                   + sh.gem.Dp[2][m][nl] + sh.gem.Dp[3][m][nl] + p.bias2[n0 + nl]);
            }
        }
        gbar(p.barCnt, bk); bk++;

        // ---- P23: e + softmax + context + gc ; block = (j=b&63, q=b>>6) ----
        int jj = b & 63, qq = b >> 6;
        int oo = p.idx[jj], wjj = p.rank[jj], ljj = p.lens[oo];
        {
            if (t < ljj){
                if (tid < 512){
                    sh.p23.att2L[tid] = ldgf(&p.D2[jj*N2 + tid]);
                    sh.p23.wfaL[tid]  = p.wfa[tid];
                }
                __syncthreads();

                int pp = tid & 255, ah = tid >> 8;
                float acc = 0.f;
                if (pp < P){
                    const short* ar = (const short*)p.att1w + (size_t)(jj*P + pp)*ATT + ah*128;
                    #pragma unroll 8
                    for (int k8 = 0; k8 < 16; ++k8){
                        bf16x8 v = *(const bf16x8*)(ar + k8*8);
                        #pragma unroll
                        for (int z=0; z<8; ++z){
                            int a = ah*128 + k8*8 + z;
                            acc += fmaxf(bfu(v[z]) + sh.p23.att2L[a], 0.f) * sh.p23.wfaL[a];
                        }
                    }
                }
                sh.p23.red[tid] = acc;
                __syncthreads();
                float e = -1e30f;
                if (tid < P) e = sh.p23.red[tid] + sh.p23.red[tid+256] + sh.p23.red[tid+512] + sh.p23.red[tid+768] + bfa0;
                __syncthreads();
                sh.p23.red[tid] = (tid < P) ? e : -1e30f;
                __syncthreads();
                for (int s = 512; s > 0; s >>= 1){
                    if (tid < s) sh.p23.red[tid] = fmaxf(sh.p23.red[tid], sh.p23.red[tid+s]);
                    __syncthreads();
                }
                float m = sh.p23.red[0];
                __syncthreads();
                float ex = (tid < P) ? __expf(e - m) : 0.f;
                sh.p23.red[tid] = ex;
                __syncthreads();
                for (int s = 512; s > 0; s >>= 1){
                    if (tid < s) sh.p23.red[tid] += sh.p23.red[tid+s];
                    __syncthreads();
                }
                float ssum = sh.p23.red[0];
                if (tid < P) sh.p23.aL[tid] = ex / ssum;
                if (tid >= P && tid < 208) sh.p23.aL[tid] = 0.f;
                __syncthreads();

                // context quarter [q*512, q*512+512) from fp8 img: wave w takes p = w, w+16, ...
                const unsigned char* ib = p.img8 + (size_t)jj*P*ENC + qq*512 + l*8;
                float a8[8];
                #pragma unroll
                for (int z=0; z<8; ++z) a8[z] = 0.f;
                #pragma unroll 4
                for (int i = 0; i < 13; ++i){
                    int pp2 = w + 16*i;
                    int pr = (pp2 < P) ? pp2 : 0;
                    uint2 v = *(const uint2*)(ib + (size_t)pr*ENC);
                    float al = sh.p23.aL[pp2];
                    f32x2 f01 = FP8_DEC2(v.x, 0);
                    f32x2 f23 = FP8_DEC2(v.x, 1);
                    f32x2 f45 = FP8_DEC2(v.y, 0);
                    f32x2 f67 = FP8_DEC2(v.y, 1);
                    a8[0] += al * f01.x; a8[1] += al * f01.y;
                    a8[2] += al * f23.x; a8[3] += al * f23.y;
                    a8[4] += al * f45.x; a8[5] += al * f45.y;
                    a8[6] += al * f67.x; a8[7] += al * f67.y;
                }
                if (w < 8){
                    #pragma unroll
                    for (int z=0; z<8; ++z) sh.p23.ctxP[w][l*8+z] = a8[z];
                }
                __syncthreads();
                if (w >= 8){
                    #pragma unroll
                    for (int z=0; z<8; ++z) sh.p23.ctxP[w-8][l*8+z] += a8[z];
                }
                __syncthreads();
                if (tid < 256){
                    int d0 = 2*tid;
                    float c0 = 0.f, c1 = 0.f;
                    #pragma unroll
                    for (int r=0; r<8; ++r){ c0 += sh.p23.ctxP[r][d0]; c1 += sh.p23.ctxP[r][d0+1]; }
                    int eg0 = qq*512 + d0;
                    float g0 = sigm(ldgf(&p.D2[jj*N2 + ATT + eg0]));
                    float g1 = sigm(ldgf(&p.D2[jj*N2 + ATT + eg0 + 1]));
                    stgu((unsigned*)((short*)gcT + jj*ENC + eg0), pkbf(g0*c0, g1*c1));
                }
            }
        }
        gbar_arrive(p.barCnt, bk);     // gc visible; do independent work in the wait shadow

        // outA write (external-only) in barrier shadow
        if (qq == 0 && tid < P){
            float av = (t < ljj) ? sh.p23.aL[tid] : 0.f;
            p.outA[((size_t)(wjj*T + t))*P + tid] = av;
        }
        __syncthreads();               // close p23 LDS usage before gem reuse

        // ---- P4 prelude + non-gc MFMA (emb + h segments) in barrier shadow ----
        if (tid < 64){
            int o = p.idx[tid];
            sh.gem.tokL[tid] = p.sent[o*T + t];
            sh.gem.lensL[tid] = p.lens[o];
            sh.gem.wLs[tid] = p.rank[tid];
        }
        __syncthreads();
        {
            int rt = w & 3, kq = w >> 2;
            bool act = (16*rt < nAct);
            int mrow = 16*rt + lm;
            f32x4 acc = {0.f,0.f,0.f,0.f};
            const short* aEmb = 0; const short* aGc = 0; const short* aH = 0;
            const bf16x8* BL = (const bf16x8*)WcatL;
            if (act){
                int tok = sh.gem.tokL[mrow];
                aEmb = (const short*)p.emb_bf + (size_t)tok*EMB + 8*lk;
                aGc  = (const short*)gcT + (size_t)mrow*ENC + 8*lk;
                aH   = (const short*)hbIn + (size_t)mrow*HID + 8*lk;
                if (kq == 0){
                    #pragma unroll 8
                    for (int kt = 0; kt < 16; ++kt){
                        bf16x8 a = *(const bf16x8*)(aEmb + kt*32);
                        acc = __builtin_amdgcn_mfma_f32_16x16x32_bf16(a, BL[kt*64 + l], acc, 0,0,0);
                    }
                } else if (kq == 2){
                    #pragma unroll
                    for (int kt = 80; kt < 84; ++kt){
                        bf16x8 a = *(const bf16x8*)(aH + (kt-80)*32);
                        acc = __builtin_amdgcn_mfma_f32_16x16x32_bf16(a, BL[kt*64 + l], acc, 0,0,0);
                    }
                } else if (kq == 3){
                    #pragma unroll 7
                    for (int kt = 84; kt < 112; ++kt){
                        bf16x8 a = *(const bf16x8*)(aH + (kt-80)*32);
                        acc = __builtin_amdgcn_mfma_f32_16x16x32_bf16(a, BL[kt*64 + l], acc, 0,0,0);
                    }
                }
            }
            gbar_wait(p.barCnt, bk); bk++;    // gc now ready

            if (act){
                if (kq == 0){
                    #pragma unroll 6
                    for (int kt = 16; kt < 28; ++kt){
                        bf16x8 a = *(const bf16x8*)(aGc + (kt-16)*32);
                        acc = __builtin_amdgcn_mfma_f32_16x16x32_bf16(a, BL[kt*64 + l], acc, 0,0,0);
                    }
                } else if (kq == 1){
                    #pragma unroll 7
                    for (int kt = 28; kt < 56; ++kt){
                        bf16x8 a = *(const bf16x8*)(aGc + (kt-16)*32);
                        acc = __builtin_amdgcn_mfma_f32_16x16x32_bf16(a, BL[kt*64 + l], acc, 0,0,0);
                    }
                } else if (kq == 2){
                    #pragma unroll 6
                    for (int kt = 56; kt < 80; ++kt){
                        bf16x8 a = *(const bf16x8*)(aGc + (kt-16)*32);
                        acc = __builtin_amdgcn_mfma_f32_16x16x32_bf16(a, BL[kt*64 + l], acc, 0,0,0);
                    }
                }
                #pragma unroll
                for (int r=0; r<4; ++r) sh.gem.Dp[kq][16*rt + 4*lk + r][lm] = acc[r];
            }
        }
        __syncthreads();

        // ---- LSTM pointwise ----
        int j2 = tid & 63, du = tid >> 6;
        int u = 4*b + du;
        float cNew = 0.f, hNew = 0.f, hKeep = 0.f, cOld = 0.f;
        bool active = false;
        if (tid < 256){
            float g4[4];
            #pragma unroll
            for (int g=0; g<4; ++g){
                int nl = 4*du + g;
                g4[g] = sh.gem.Dp[0][j2][nl] + sh.gem.Dp[1][j2][nl]
                      + sh.gem.Dp[2][j2][nl] + sh.gem.Dp[3][j2][nl] + p.bsum[16*b + nl];
            }
            float ig = sigm(g4[0]), fg = sigm(g4[1]), gg = tanhf(g4[2]), og = sigm(g4[3]);
            cOld = p.cW[j2*HID + u];
            cNew = fg*cOld + ig*gg;
            hNew = og*tanhf(cNew);
            active = (t < sh.gem.lensL[j2]);
            float hOld = hFIn[j2*HID + u];
            hKeep = active ? hNew : hOld;
            sh.gem.hS[j2][du] = hKeep;
        }
        __syncthreads();
        if (tid < 128){
            int jb = tid & 63, dp = tid >> 6;
            int u0 = 4*b + 2*dp;
            stgu((unsigned*)((short*)hbOut + jb*HID + u0),
                 pkbf(sh.gem.hS[jb][2*dp], sh.gem.hS[jb][2*dp+1]));
        }
        gbar_arrive(p.barCnt, bk);     // h(t+1) visible; private/external stores in shadow
        if (tid < 256){
            p.cW[j2*HID + u] = active ? cNew : cOld;
            hFOut[j2*HID + u] = hKeep;
            p.outH[((size_t)sh.gem.wLs[j2]*T + t)*HID + u] = active ? hNew : 0.f;
        }
        gbar_wait(p.barCnt, bk); bk++;
    }
}

extern "C" void kernel_launch(void* const* d_in, const int* in_sizes, int n_in,
                              void* d_out, int out_size, void* d_ws, size_t ws_size,
                              hipStream_t stream) {
    const float* img   = (const float*)d_in[0];
    const int*   sent  = (const int*)  d_in[1];
    const float* enc_h = (const float*)d_in[2];
    const float* enc_c = (const float*)d_in[3];
    const int*   lens  = (const int*)  d_in[4];
    const float* emb   = (const float*)d_in[5];
    const float* Wea   = (const float*)d_in[6];
    const float* bea   = (const float*)d_in[7];
    const float* Wda   = (const float*)d_in[8];
    const float* bda   = (const float*)d_in[9];
    const float* wfa   = (const float*)d_in[10];
    const float* bfa   = (const float*)d_in[11];
    const float* Wfb   = (const float*)d_in[12];
    const float* bfb   = (const float*)d_in[13];
    const float* Wih   = (const float*)d_in[14];
    const float* bih   = (const float*)d_in[15];
    const float* Whh   = (const float*)d_in[16];
    const float* bhh   = (const float*)d_in[17];

    float* outH = (float*)d_out;                       // [B,T,HID] f32
    float* outA = outH + (size_t)B*T*HID;              // [B,T,P]  f32

    char* wsb = (char*)d_ws;
    size_t off = 0;
    int* idxW  = (int*)(wsb + off); off += 256;
    int* rankW = (int*)(wsb + off); off += 256;
    int* nActW = (int*)(wsb + off); off += 1024;
    unsigned* barCnt = (unsigned*)(wsb + off); off += 131072;   // arr 64KB + gdone 4KB + rel 4KB (padded)
    __hip_bfloat16* att1w = (__hip_bfloat16*)(wsb + off); off += (size_t)B*P*ATT*2;       // 12.85MB
    unsigned char* img8 = (unsigned char*)(wsb + off); off += (size_t)B*P*ENC;            // 25.69MB (fp8)
    __hip_bfloat16* emb_bf= (__hip_bfloat16*)(wsb + off); off += (size_t)10000*EMB*2;     // 10.24MB
    __hip_bfloat16* Wfrag = (__hip_bfloat16*)(wsb + off); off += (size_t)4*HID*KTOT*2;    // 29.36MB
    __hip_bfloat16* W2    = (__hip_bfloat16*)(wsb + off); off += (size_t)N2*HID*2;        // 5.24MB
    __hip_bfloat16* Wea_bf= (__hip_bfloat16*)(wsb + off); off += (size_t)ATT*ENC*2;       // 2.10MB (prologue-only)
    float* bsum  = (float*)(wsb + off); off += 4*HID*4;
    float* bias2 = (float*)(wsb + off); off += N2*4;
    float* hA    = (float*)(wsb + off); off += B*HID*4;
    float* hB    = (float*)(wsb + off); off += B*HID*4;
    float* cWs   = (float*)(wsb + off); off += B*HID*4;
    float* D2    = (float*)(wsb + off); off += (size_t)B*N2*4;
    __hip_bfloat16* gcR = (__hip_bfloat16*)(wsb + off); off += (size_t)T*B*ENC*2;         // 41.9MB rotating
    __hip_bfloat16* hbR = (__hip_bfloat16*)(wsb + off); off += (size_t)(T+1)*B*HID*2;     // 21.1MB rotating

    k_sort<<<1, 64, 0, stream>>>(lens, idxW, rankW, barCnt, nActW);
    k_init_hc<<<B, 256, 0, stream>>>(enc_h, enc_c, idxW, hA, cWs, hbR);
    k_cvt_wcat<<<57344, 256, 0, stream>>>(Wih, Whh, Wfrag);
    k_bsum<<<16, 256, 0, stream>>>(bih, bhh, bsum);
    k_cvt_w2<<<N2, 256, 0, stream>>>(Wda, bda, Wfb, bfb, W2, bias2);
    k_cvt_emb<<<20000, 256, 0, stream>>>(emb, emb_bf);
    k_cvt_wea<<<ATT, 256, 0, stream>>>(Wea, Wea_bf);
    k_cvt_img8<<<dim3(P*ENC/256, B), 256, 0, stream>>>(img, idxW, img8);
    k_att1m<<<dim3((B*P)/64, ATT/64), 256, 0, stream>>>(img, idxW, Wea_bf, bea, att1w);

    SP sp;
    sp.att1w = att1w; sp.img8 = img8; sp.emb_bf = emb_bf; sp.Wfrag = Wfrag; sp.W2 = W2;
    sp.bsum = bsum; sp.bias2 = bias2; sp.wfa = wfa; sp.bfa = bfa;
    sp.sent = sent; sp.idx = idxW; sp.rank = rankW; sp.lens = lens; sp.nAct = nActW;
    sp.D2 = D2; sp.gcR = gcR; sp.hbR = hbR;
    sp.hF0 = hA; sp.hF1 = hB; sp.cW = cWs;
    sp.outH = outH; sp.outA = outA;
    sp.barCnt = barCnt;

    void* args[] = { &sp };
    hipLaunchCooperativeKernel(reinterpret_cast<void*>(k_scan), dim3(NBLK), dim3(NTHR),
                               args, 0, stream);
}

// Round 19
// 6732.858 us; speedup vs baseline: 1.0571x; 1.0225x over previous
//
#include <hip/hip_runtime.h>
#include <hip/hip_bf16.h>
#include <math.h>

#define B 64
#define T 160
#define P 196
#define ENC 2048
#define ATT 512
#define EMB 512
#define HID 1024
#define KTOT 3584   // EMB + ENC + HID
#define N2 2560     // ATT + ENC
#define KT4 112     // KTOT/32
#define NTHR 1024
#define NBLK 256

typedef __attribute__((ext_vector_type(8))) short bf16x8;
typedef __attribute__((ext_vector_type(4))) float f32x4;
typedef __attribute__((ext_vector_type(2))) float f32x2;

__device__ __forceinline__ float sigm(float x){ return 1.0f/(1.0f+__expf(-x)); }
__device__ __forceinline__ float bfu(short s){ return __uint_as_float(((unsigned)(unsigned short)s) << 16); }
__device__ __forceinline__ short f2bf(float x){ __hip_bfloat16 h = __float2bfloat16(x); return *(short*)&h; }

// ---- fp8 e4m3fn decode (hot path) ----
#if __has_builtin(__builtin_amdgcn_cvt_pk_f32_fp8)
#define FP8_DEC2(w, sel) __builtin_amdgcn_cvt_pk_f32_fp8((int)(w), (sel))
#else
__device__ __forceinline__ float fp8dec1(unsigned b){
    unsigned s = b >> 7, e = (b >> 3) & 15, m = b & 7;
    float v = e ? __uint_as_float(((e + 120u) << 23) | (m << 20)) : (float)(int)m * 0.001953125f;
    return s ? -v : v;
}
__device__ __forceinline__ f32x2 FP8_DEC2(unsigned w, int sel){
    unsigned h = sel ? (w >> 16) : (w & 0xFFFFu);
    f32x2 r; r.x = fp8dec1(h & 0xFF); r.y = fp8dec1(h >> 8);
    return r;
}
#endif

// ---- fp8 e4m3fn encode (prologue only, manual RNE) ----
__device__ __forceinline__ unsigned char fp8enc(float x){
    unsigned bits = __float_as_uint(x);
    unsigned s = (bits >> 31) << 7;
    unsigned abits = bits & 0x7FFFFFFFu;
    float a = __uint_as_float(abits);
    if (a >= 448.f) return (unsigned char)(s | 0x7E);
    if (a < 0.0009765625f) return (unsigned char)s;
    int E = (int)(abits >> 23) - 127;
    if (E < -6){
        int q = (int)rintf(a * 512.0f);
        if (q >= 8) return (unsigned char)(s | 0x08);
        return (unsigned char)(s | q);
    }
    unsigned m23 = abits & 0x7FFFFFu;
    unsigned r = (m23 + 0x7FFFFu + ((m23 >> 20) & 1u)) >> 20;
    if (r >= 8){ r = 0; E++; }
    if (E > 8 || (E == 8 && r > 6)) return (unsigned char)(s | 0x7E);
    return (unsigned char)(s | ((unsigned)(E + 7) << 3) | r);
}

// ---- MALL-coherent movement for cross-block data (volatile => sc0 sc1) ----
__device__ __forceinline__ float ldgf(const float* p){ return *(const volatile float*)p; }
__device__ __forceinline__ void stgf(float* p, float v){ *(volatile float*)p = v; }
__device__ __forceinline__ void stgu(unsigned* p, unsigned v){ *(volatile unsigned*)p = v; }
__device__ __forceinline__ unsigned pkbf(float a, float b){
    unsigned ua = (unsigned)__bfloat16_as_ushort(__float2bfloat16(a));
    unsigned ub = (unsigned)__bfloat16_as_ushort(__float2bfloat16(b));
    return ua | (ub << 16);
}

// ---- dataflow sync: per-block monotone phase flags (64B stride) ----
// flag[b] = pi after block b completes a phase. pi = 3t+1 (P1), 3t+2 (P23), 3t+3 (P4).
__device__ __forceinline__ void arrive(unsigned* bar, unsigned pi){
    asm volatile("s_waitcnt vmcnt(0)" ::: "memory");   // our data stores acked first
    __syncthreads();
    if (threadIdx.x == 0)
        *(volatile unsigned*)(bar + (unsigned)blockIdx.x*16) = pi;
}
// each lane of the calling wave polls ONE flag (flagIdx per-lane), until >= target
__device__ __forceinline__ void wave_wait(unsigned* bar, int flagIdx, unsigned target){
    volatile unsigned* s = (volatile unsigned*)(bar + flagIdx*16);
    while (!__all(*s >= target)) __builtin_amdgcn_s_sleep(1);
    asm volatile("" ::: "memory");
}
// one wave sweeps all 256 flags (4 per lane)
__device__ __forceinline__ void wave_wait_all(unsigned* bar, unsigned target){
    int l = threadIdx.x & 63;
    volatile unsigned* s0 = (volatile unsigned*)(bar + l*16);
    volatile unsigned* s1 = (volatile unsigned*)(bar + (l+64)*16);
    volatile unsigned* s2 = (volatile unsigned*)(bar + (l+128)*16);
    volatile unsigned* s3 = (volatile unsigned*)(bar + (l+192)*16);
    for (;;){
        unsigned a = *s0, b = *s1, c = *s2, d = *s3;
        unsigned mn = min(min(a,b), min(c,d));
        if (__all(mn >= target)) break;
        __builtin_amdgcn_s_sleep(1);
    }
    asm volatile("" ::: "memory");
}

// ---------- sort + nAct table ----------
__global__ void k_sort(const int* lens, int* idx, int* rank, unsigned* barCnt, int* nAct){
    __shared__ int L[B];
    int i = threadIdx.x;
    L[i] = lens[i];
    for (int s = i; s < 256; s += B) barCnt[s*16] = 0u;
    __syncthreads();
    int li = L[i];
    int r = 0;
    for (int j = 0; j < B; ++j){
        int lj = L[j];
        if (lj > li || (lj == li && j < i)) r++;
    }
    rank[i] = r;
    idx[r] = i;
    for (int tt = i; tt < T; tt += B){
        int c = 0;
        for (int j = 0; j < B; ++j) c += (L[j] > tt) ? 1 : 0;
        nAct[tt] = c;
    }
}

// ---------- init h0/c0 (sorted) + bf16 copy into hbR slot 0 ----------
__global__ void k_init_hc(const float* enc_h, const float* enc_c, const int* idx,
                          float* h, float* c, __hip_bfloat16* hbR0){
    int j = blockIdx.x;
    int o = idx[j];
    for (int k = threadIdx.x; k < HID; k += blockDim.x){
        float hv = (k < 512) ? enc_h[o*512 + k] : enc_h[B*512 + o*512 + (k-512)];
        float cv = (k < 512) ? enc_c[o*512 + k] : enc_c[B*512 + o*512 + (k-512)];
        h[j*HID + k] = hv;
        c[j*HID + k] = cv;
        hbR0[j*HID + k] = __float2bfloat16(hv);
    }
}

// ---------- Wcat in per-strip MFMA-fragment order (once) ----------
__global__ void k_cvt_wcat(const float* Wih, const float* Whh, __hip_bfloat16* Wfrag){
    size_t i = (size_t)blockIdx.x*256 + threadIdx.x;
    int e = (int)(i & 7);
    size_t t2 = i >> 3;
    int lane = (int)(t2 & 63);
    size_t t3 = t2 >> 6;
    int kt = (int)(t3 % KT4);
    int strip = (int)(t3 / KT4);
    int n = strip*16 + (lane & 15);
    int r = (n & 3)*HID + (n >> 2);
    int k = kt*32 + (lane >> 4)*8 + e;
    float v = (k < EMB+ENC) ? Wih[(size_t)r*(EMB+ENC) + k]
                            : Whh[(size_t)r*HID + (k - EMB - ENC)];
    Wfrag[i] = __float2bfloat16(v);
}

__global__ void k_bsum(const float* bih, const float* bhh, float* bsum){
    int n = blockIdx.x*256 + threadIdx.x;
    int r = (n & 3)*HID + (n >> 2);
    bsum[n] = bih[r] + bhh[r];
}

__global__ void k_cvt_w2(const float* Wda, const float* bda, const float* Wfb, const float* bfb,
                         __hip_bfloat16* W2, float* bias2){
    int n = blockIdx.x;
    const float* src = (n < ATT) ? (Wda + (size_t)n*HID) : (Wfb + (size_t)(n-ATT)*HID);
    __hip_bfloat16* dst = W2 + (size_t)n*HID;
    for (int k = threadIdx.x; k < HID; k += 256) dst[k] = __float2bfloat16(src[k]);
    if (threadIdx.x == 0) bias2[n] = (n < ATT) ? bda[n] : bfb[n-ATT];
}

__global__ void k_cvt_emb(const float* emb, __hip_bfloat16* emb_bf){
    size_t i = (size_t)blockIdx.x*256 + threadIdx.x;
    emb_bf[i] = __float2bfloat16(emb[i]);
}

__global__ void k_cvt_wea(const float* Wea, __hip_bfloat16* Wea_bf){
    int n = blockIdx.x;
    for (int k = threadIdx.x; k < ENC; k += 256)
        Wea_bf[(size_t)n*ENC + k] = __float2bfloat16(Wea[(size_t)n*ENC + k]);
}

// img fp32 -> fp8 e4m3 (sorted order)
__global__ void k_cvt_img8(const float* img, const int* idx, unsigned char* img8){
    int j = blockIdx.y;
    int o = idx[j];
    size_t off = (size_t)blockIdx.x*256 + threadIdx.x;
    img8[(size_t)j*P*ENC + off] = fp8enc(img[(size_t)o*P*ENC + off]);
}

// ---------- att1 (once, MFMA): A from fp32 img (gather+cvt), B = Wea_bf ----------
__global__ __launch_bounds__(256) void k_att1m(const float* img, const int* idx,
                                               const __hip_bfloat16* Wea_bf,
                                               const float* bea, __hip_bfloat16* att1w){
    int m0 = blockIdx.x * 64, n0 = blockIdx.y * 64;
    int tid = threadIdx.x, w = tid >> 6, l = tid & 63, lm = l & 15, lk = l >> 4;
    int g = m0 + 16*w + lm;
    int j = g / P, pp2 = g - j*P;
    int o = idx[j];
    const float* af = img + ((size_t)o*P + pp2)*ENC + 8*lk;
    const short* bp = (const short*)Wea_bf + (size_t)(n0 + lm)*ENC + 8*lk;
    f32x4 acc[4];
    #pragma unroll
    for (int nt=0; nt<4; ++nt) acc[nt] = (f32x4){0.f,0.f,0.f,0.f};
    #pragma unroll 4
    for (int kt = 0; kt < ENC/32; ++kt){
        float4 f0 = *(const float4*)(af + kt*32);
        float4 f1 = *(const float4*)(af + kt*32 + 4);
        bf16x8 a;
        a[0]=f2bf(f0.x); a[1]=f2bf(f0.y); a[2]=f2bf(f0.z); a[3]=f2bf(f0.w);
        a[4]=f2bf(f1.x); a[5]=f2bf(f1.y); a[6]=f2bf(f1.z); a[7]=f2bf(f1.w);
        #pragma unroll
        for (int nt=0; nt<4; ++nt){
            bf16x8 bb = *(const bf16x8*)(bp + (size_t)nt*16*ENC + kt*32);
            acc[nt] = __builtin_amdgcn_mfma_f32_16x16x32_bf16(a, bb, acc[nt], 0,0,0);
        }
    }
    #pragma unroll
    for (int nt=0; nt<4; ++nt){
        int n = n0 + nt*16 + lm;
        float bv = bea[n];
        #pragma unroll
        for (int r=0; r<4; ++r){
            int m = m0 + 16*w + 4*lk + r;
            att1w[(size_t)m*ATT + n] = __float2bfloat16(acc[nt][r] + bv);
        }
    }
}

// ---------- persistent cooperative scan ----------
struct SP {
    const __hip_bfloat16 *att1w, *emb_bf, *Wfrag, *W2;
    const unsigned char *img8;
    const float *bsum, *bias2, *wfa, *bfa;
    const int *sent, *idx, *rank, *lens, *nAct;
    float *D2;
    __hip_bfloat16 *gcR, *hbR;     // rotating: gcR[t], hbR[t] (hbR has T+1 slots)
    float *hF0, *hF1, *cW;
    float *outH, *outA;
    unsigned *barCnt;
};

__global__ __launch_bounds__(1024, 4) void k_scan(SP p){
    __shared__ short WcatL[KT4*64*8];          // 114,688 B, fragment-ordered
    __shared__ union {
        struct { float Dp[4][64][17]; float hS[64][4]; int tokL[64], lensL[64], wLs[64]; } gem;
        struct { float att2L[512]; float wfaL[512]; float red[1024]; float aL[208]; float ctxP[8][512]; } p23;
    } sh;

    int b = blockIdx.x, tid = threadIdx.x;
    int w = tid >> 6, l = tid & 63, lm = l & 15, lk = l >> 4;

    // one-time LDS fill (straight copy, frag order)
    {
        const bf16x8* src = (const bf16x8*)((const short*)p.Wfrag + (size_t)b*KT4*64*8);
        bf16x8* dst = (bf16x8*)WcatL;
        #pragma unroll
        for (int i = 0; i < KT4*64/NTHR; ++i) dst[tid + i*NTHR] = src[tid + i*NTHR];
    }
    __syncthreads();

    float bfa0 = p.bfa[0];
    int jj = b & 63, qq = b >> 6;

    for (int t = 0; t < T; ++t){
        const __hip_bfloat16* hbIn = p.hbR + (size_t)t*B*HID;
        __hip_bfloat16*       hbOut = p.hbR + (size_t)(t+1)*B*HID;
        const __hip_bfloat16* gcT  = p.gcR + (size_t)t*B*ENC;
        const float* hFIn = (t & 1) ? p.hF1 : p.hF0;
        float*       hFOut = (t & 1) ? p.hF0 : p.hF1;
        int nAct = p.nAct[t];
        unsigned pi0 = 3u*(unsigned)t;     // P4(t-1) ordinal

        // ---- P1: D2[64][2560] = h_bf @ W2^T + bias2 ; blocks < 160, 4-way K-split ----
        if (b < N2/16){
            int n0 = b*16;
            int rt = w & 3, kq = w >> 2;
            // per-wave wait: only the 64 P4(t-1) blocks owning u in [256kq, 256kq+256)
            wave_wait(p.barCnt, 64*kq + l, pi0);
            if (16*rt < nAct){
                const short* ap = (const short*)hbIn + (size_t)(16*rt + lm)*HID + kq*256 + 8*lk;
                const short* bp = (const short*)p.W2 + (size_t)(n0 + lm)*HID + kq*256 + 8*lk;
                f32x4 acc = {0.f,0.f,0.f,0.f};
                #pragma unroll
                for (int kt = 0; kt < 8; ++kt){
                    bf16x8 a = *(const bf16x8*)(ap + kt*32);
                    bf16x8 bb = *(const bf16x8*)(bp + kt*32);
                    acc = __builtin_amdgcn_mfma_f32_16x16x32_bf16(a, bb, acc, 0,0,0);
                }
                #pragma unroll
                for (int r=0; r<4; ++r) sh.gem.Dp[kq][16*rt + 4*lk + r][lm] = acc[r];
            }
            __syncthreads();
            int m = tid >> 4, nl = tid & 15;
            if (m < nAct){
                stgf(&p.D2[m*N2 + n0 + nl],
                     sh.gem.Dp[0][m][nl] + sh.gem.Dp[1][m][nl]
                   + sh.gem.Dp[2][m][nl] + sh.gem.Dp[3][m][nl] + p.bias2[n0 + nl]);
            }
            arrive(p.barCnt, pi0 + 1u);     // blocks < 160 only
        }

        // ---- P23 producer wait: ALL blocks (also guarantees hbR[t] fully visible
        //      before ANY normal-cached read of it in the P4 prelude — prevents the
        //      stale-L2-fill race from inactive blocks racing ahead) ----
        if (w == 0){
            int fi = (l < 32) ? l : (32*qq + l);
            wave_wait(p.barCnt, fi, pi0 + 1u);
        }
        __syncthreads();

        // ---- P23: e + softmax + context + gc ; block = (j=b&63, q=b>>6) ----
        int ljj = p.lens[p.idx[jj]];
        int wjj = p.rank[jj];
        if (t < ljj){
            if (tid < 512){
                sh.p23.att2L[tid] = ldgf(&p.D2[jj*N2 + tid]);
                sh.p23.wfaL[tid]  = p.wfa[tid];
            }
            __syncthreads();

            int pp = tid & 255, ah = tid >> 8;
            float acc = 0.f;
            if (pp < P){
                const short* ar = (const short*)p.att1w + (size_t)(jj*P + pp)*ATT + ah*128;
                #pragma unroll 8
                for (int k8 = 0; k8 < 16; ++k8){
                    bf16x8 v = *(const bf16x8*)(ar + k8*8);
                    #pragma unroll
                    for (int z=0; z<8; ++z){
                        int a = ah*128 + k8*8 + z;
                        acc += fmaxf(bfu(v[z]) + sh.p23.att2L[a], 0.f) * sh.p23.wfaL[a];
                    }
                }
            }
            sh.p23.red[tid] = acc;
            __syncthreads();
            float e = -1e30f;
            if (tid < P) e = sh.p23.red[tid] + sh.p23.red[tid+256] + sh.p23.red[tid+512] + sh.p23.red[tid+768] + bfa0;
            // wave-level softmax reduce (waves 0..3 hold the 256 row-slots)
            float* sm  = &sh.p23.red[976];
            float* sm2 = &sh.p23.red[984];
            if (tid < 256){
                float mv = e;
                #pragma unroll
                for (int off = 32; off; off >>= 1) mv = fmaxf(mv, __shfl_xor(mv, off, 64));
                if (l == 0) sm[w] = mv;
            }
            __syncthreads();
            float m = fmaxf(fmaxf(sm[0], sm[1]), fmaxf(sm[2], sm[3]));
            float ex = (tid < P) ? __expf(e - m) : 0.f;
            if (tid < 256){
                float sv = ex;
                #pragma unroll
                for (int off = 32; off; off >>= 1) sv += __shfl_xor(sv, off, 64);
                if (l == 0) sm2[w] = sv;
            }
            __syncthreads();
            float ssum = sm2[0] + sm2[1] + sm2[2] + sm2[3];
            if (tid < P) sh.p23.aL[tid] = ex / ssum;
            if (tid >= P && tid < 208) sh.p23.aL[tid] = 0.f;
            __syncthreads();

            // context quarter [q*512, q*512+512) from fp8 img: wave w takes p = w, w+16, ...
            const unsigned char* ib = p.img8 + (size_t)jj*P*ENC + qq*512 + l*8;
            float a8[8];
            #pragma unroll
            for (int z=0; z<8; ++z) a8[z] = 0.f;
            #pragma unroll 4
            for (int i = 0; i < 13; ++i){
                int pp2 = w + 16*i;
                int pr = (pp2 < P) ? pp2 : 0;
                uint2 v = *(const uint2*)(ib + (size_t)pr*ENC);
                float al = sh.p23.aL[pp2];
                f32x2 f01 = FP8_DEC2(v.x, 0);
                f32x2 f23 = FP8_DEC2(v.x, 1);
                f32x2 f45 = FP8_DEC2(v.y, 0);
                f32x2 f67 = FP8_DEC2(v.y, 1);
                a8[0] += al * f01.x; a8[1] += al * f01.y;
                a8[2] += al * f23.x; a8[3] += al * f23.y;
                a8[4] += al * f45.x; a8[5] += al * f45.y;
                a8[6] += al * f67.x; a8[7] += al * f67.y;
            }
            if (w < 8){
                #pragma unroll
                for (int z=0; z<8; ++z) sh.p23.ctxP[w][l*8+z] = a8[z];
            }
            __syncthreads();
            if (w >= 8){
                #pragma unroll
                for (int z=0; z<8; ++z) sh.p23.ctxP[w-8][l*8+z] += a8[z];
            }
            __syncthreads();
            if (tid < 256){
                int d0 = 2*tid;
                float c0 = 0.f, c1 = 0.f;
                #pragma unroll
                for (int r=0; r<8; ++r){ c0 += sh.p23.ctxP[r][d0]; c1 += sh.p23.ctxP[r][d0+1]; }
                int eg0 = qq*512 + d0;
                float g0 = sigm(ldgf(&p.D2[jj*N2 + ATT + eg0]));
                float g1 = sigm(ldgf(&p.D2[jj*N2 + ATT + eg0 + 1]));
                stgu((unsigned*)((short*)gcT + jj*ENC + eg0), pkbf(g0*c0, g1*c1));
            }
        }
        arrive(p.barCnt, pi0 + 2u);     // gc visible; independent work in the wait shadow

        // outA write (external-only) in barrier shadow
        if (qq == 0 && tid < P){
            float av = (t < ljj) ? sh.p23.aL[tid] : 0.f;
            p.outA[((size_t)(wjj*T + t))*P + tid] = av;
        }
        __syncthreads();               // close p23 LDS usage before gem reuse

        // ---- P4 prelude + non-gc MFMA (emb + h segments) in barrier shadow ----
        if (tid < 64){
            int o = p.idx[tid];
            sh.gem.tokL[tid] = p.sent[o*T + t];
            sh.gem.lensL[tid] = p.lens[o];
            sh.gem.wLs[tid] = p.rank[tid];
        }
        __syncthreads();
        {
            int rt = w & 3, kq = w >> 2;
            bool act = (16*rt < nAct);
            int mrow = 16*rt + lm;
            f32x4 acc = {0.f,0.f,0.f,0.f};
            const short* aEmb = 0; const short* aGc = 0; const short* aH = 0;
            const bf16x8* BL = (const bf16x8*)WcatL;
            if (act){
                int tok = sh.gem.tokL[mrow];
                aEmb = (const short*)p.emb_bf + (size_t)tok*EMB + 8*lk;
                aGc  = (const short*)gcT + (size_t)mrow*ENC + 8*lk;
                aH   = (const short*)hbIn + (size_t)mrow*HID + 8*lk;
                if (kq == 0){
                    #pragma unroll 8
                    for (int kt = 0; kt < 16; ++kt){
                        bf16x8 a = *(const bf16x8*)(aEmb + kt*32);
                        acc = __builtin_amdgcn_mfma_f32_16x16x32_bf16(a, BL[kt*64 + l], acc, 0,0,0);
                    }
                } else if (kq == 2){
                    #pragma unroll
                    for (int kt = 80; kt < 84; ++kt){
                        bf16x8 a = *(const bf16x8*)(aH + (kt-80)*32);
                        acc = __builtin_amdgcn_mfma_f32_16x16x32_bf16(a, BL[kt*64 + l], acc, 0,0,0);
                    }
                } else if (kq == 3){
                    #pragma unroll 7
                    for (int kt = 84; kt < 112; ++kt){
                        bf16x8 a = *(const bf16x8*)(aH + (kt-80)*32);
                        acc = __builtin_amdgcn_mfma_f32_16x16x32_bf16(a, BL[kt*64 + l], acc, 0,0,0);
                    }
                }
            }
            // full wait: P4 needs all 256 gc producers
            if (tid < 64) wave_wait_all(p.barCnt, pi0 + 2u);
            __syncthreads();

            if (act){
                if (kq == 0){
                    #pragma unroll 6
                    for (int kt = 16; kt < 28; ++kt){
                        bf16x8 a = *(const bf16x8*)(aGc + (kt-16)*32);
                        acc = __builtin_amdgcn_mfma_f32_16x16x32_bf16(a, BL[kt*64 + l], acc, 0,0,0);
                    }
                } else if (kq == 1){
                    #pragma unroll 7
                    for (int kt = 28; kt < 56; ++kt){
                        bf16x8 a = *(const bf16x8*)(aGc + (kt-16)*32);
                        acc = __builtin_amdgcn_mfma_f32_16x16x32_bf16(a, BL[kt*64 + l], acc, 0,0,0);
                    }
                } else if (kq == 2){
                    #pragma unroll 6
                    for (int kt = 56; kt < 80; ++kt){
                        bf16x8 a = *(const bf16x8*)(aGc + (kt-16)*32);
                        acc = __builtin_amdgcn_mfma_f32_16x16x32_bf16(a, BL[kt*64 + l], acc, 0,0,0);
                    }
                }
                #pragma unroll
                for (int r=0; r<4; ++r) sh.gem.Dp[kq][16*rt + 4*lk + r][lm] = acc[r];
            }
        }
        __syncthreads();

        // ---- LSTM pointwise ----
        int j2 = tid & 63, du = tid >> 6;
        int u = 4*b + du;
        float cNew = 0.f, hNew = 0.f, hKeep = 0.f, cOld = 0.f;
        bool active = false;
        if (tid < 256){
            float g4[4];
            #pragma unroll
            for (int g=0; g<4; ++g){
                int nl = 4*du + g;
                g4[g] = sh.gem.Dp[0][j2][nl] + sh.gem.Dp[1][j2][nl]
                      + sh.gem.Dp[2][j2][nl] + sh.gem.Dp[3][j2][nl] + p.bsum[16*b + nl];
            }
            float ig = sigm(g4[0]), fg = sigm(g4[1]), gg = tanhf(g4[2]), og = sigm(g4[3]);
            cOld = p.cW[j2*HID + u];
            cNew = fg*cOld + ig*gg;
            hNew = og*tanhf(cNew);
            active = (t < sh.gem.lensL[j2]);
            float hOld = hFIn[j2*HID + u];
            hKeep = active ? hNew : hOld;
            sh.gem.hS[j2][du] = hKeep;
        }
        __syncthreads();
        if (tid < 128){
            int jb = tid & 63, dp = tid >> 6;
            int u0 = 4*b + 2*dp;
            stgu((unsigned*)((short*)hbOut + jb*HID + u0),
                 pkbf(sh.gem.hS[jb][2*dp], sh.gem.hS[jb][2*dp+1]));
        }
        arrive(p.barCnt, pi0 + 3u);    // h(t+1) visible; private/external stores in shadow
        if (tid < 256){
            p.cW[j2*HID + u] = active ? cNew : cOld;
            hFOut[j2*HID + u] = hKeep;
            p.outH[((size_t)sh.gem.wLs[j2]*T + t)*HID + u] = active ? hNew : 0.f;
        }
        // no full wait here: next step's consumers do their own producer-subset waits
    }
}

extern "C" void kernel_launch(void* const* d_in, const int* in_sizes, int n_in,
                              void* d_out, int out_size, void* d_ws, size_t ws_size,
                              hipStream_t stream) {
    const float* img   = (const float*)d_in[0];
    const int*   sent  = (const int*)  d_in[1];
    const float* enc_h = (const float*)d_in[2];
    const float* enc_c = (const float*)d_in[3];
    const int*   lens  = (const int*)  d_in[4];
    const float* emb   = (const float*)d_in[5];
    const float* Wea   = (const float*)d_in[6];
    const float* bea   = (const float*)d_in[7];
    const float* Wda   = (const float*)d_in[8];
    const float* bda   = (const float*)d_in[9];
    const float* wfa   = (const float*)d_in[10];
    const float* bfa   = (const float*)d_in[11];
    const float* Wfb   = (const float*)d_in[12];
    const float* bfb   = (const float*)d_in[13];
    const float* Wih   = (const float*)d_in[14];
    const float* bih   = (const float*)d_in[15];
    const float* Whh   = (const float*)d_in[16];
    const float* bhh   = (const float*)d_in[17];

    float* outH = (float*)d_out;                       // [B,T,HID] f32
    float* outA = outH + (size_t)B*T*HID;              // [B,T,P]  f32

    char* wsb = (char*)d_ws;
    size_t off = 0;
    int* idxW  = (int*)(wsb + off); off += 256;
    int* rankW = (int*)(wsb + off); off += 256;
    int* nActW = (int*)(wsb + off); off += 1024;
    unsigned* barCnt = (unsigned*)(wsb + off); off += 32768;   // 256 flags x 64B (+pad)
    __hip_bfloat16* att1w = (__hip_bfloat16*)(wsb + off); off += (size_t)B*P*ATT*2;       // 12.85MB
    unsigned char* img8 = (unsigned char*)(wsb + off); off += (size_t)B*P*ENC;            // 25.69MB (fp8)
    __hip_bfloat16* emb_bf= (__hip_bfloat16*)(wsb + off); off += (size_t)10000*EMB*2;     // 10.24MB
    __hip_bfloat16* Wfrag = (__hip_bfloat16*)(wsb + off); off += (size_t)4*HID*KTOT*2;    // 29.36MB
    __hip_bfloat16* W2    = (__hip_bfloat16*)(wsb + off); off += (size_t)N2*HID*2;        // 5.24MB
    __hip_bfloat16* Wea_bf= (__hip_bfloat16*)(wsb + off); off += (size_t)ATT*ENC*2;       // 2.10MB (prologue-only)
    float* bsum  = (float*)(wsb + off); off += 4*HID*4;
    float* bias2 = (float*)(wsb + off); off += N2*4;
    float* hA    = (float*)(wsb + off); off += B*HID*4;
    float* hB    = (float*)(wsb + off); off += B*HID*4;
    float* cWs   = (float*)(wsb + off); off += B*HID*4;
    float* D2    = (float*)(wsb + off); off += (size_t)B*N2*4;
    __hip_bfloat16* gcR = (__hip_bfloat16*)(wsb + off); off += (size_t)T*B*ENC*2;         // 41.9MB rotating
    __hip_bfloat16* hbR = (__hip_bfloat16*)(wsb + off); off += (size_t)(T+1)*B*HID*2;     // 21.1MB rotating

    k_sort<<<1, 64, 0, stream>>>(lens, idxW, rankW, barCnt, nActW);
    k_init_hc<<<B, 256, 0, stream>>>(enc_h, enc_c, idxW, hA, cWs, hbR);
    k_cvt_wcat<<<57344, 256, 0, stream>>>(Wih, Whh, Wfrag);
    k_bsum<<<16, 256, 0, stream>>>(bih, bhh, bsum);
    k_cvt_w2<<<N2, 256, 0, stream>>>(Wda, bda, Wfb, bfb, W2, bias2);
    k_cvt_emb<<<20000, 256, 0, stream>>>(emb, emb_bf);
    k_cvt_wea<<<ATT, 256, 0, stream>>>(Wea, Wea_bf);
    k_cvt_img8<<<dim3(P*ENC/256, B), 256, 0, stream>>>(img, idxW, img8);
    k_att1m<<<dim3((B*P)/64, ATT/64), 256, 0, stream>>>(img, idxW, Wea_bf, bea, att1w);

    SP sp;
    sp.att1w = att1w; sp.img8 = img8; sp.emb_bf = emb_bf; sp.Wfrag = Wfrag; sp.W2 = W2;
    sp.bsum = bsum; sp.bias2 = bias2; sp.wfa = wfa; sp.bfa = bfa;
    sp.sent = sent; sp.idx = idxW; sp.rank = rankW; sp.lens = lens; sp.nAct = nActW;
    sp.D2 = D2; sp.gcR = gcR; sp.hbR = hbR;
    sp.hF0 = hA; sp.hF1 = hB; sp.cW = cWs;
    sp.outH = outH; sp.outA = outA;
    sp.barCnt = barCnt;

    void* args[] = { &sp };
    hipLaunchCooperativeKernel(reinterpret_cast<void*>(k_scan), dim3(NBLK), dim3(NTHR),
                               args, 0, stream);
}

// Round 21
// 6632.558 us; speedup vs baseline: 1.0731x; 1.0151x over previous
//
#include <hip/hip_runtime.h>
#include <hip/hip_bf16.h>
#include <math.h>

#define B 64
#define T 160
#define P 196
#define ENC 2048
#define ATT 512
#define EMB 512
#define HID 1024
#define KTOT 3584   // EMB + ENC + HID
#define N2 2560     // ATT + ENC
#define KT4 112     // KTOT/32
#define NTHR 1024
#define NBLK 256

typedef __attribute__((ext_vector_type(8))) short bf16x8;
typedef __attribute__((ext_vector_type(4))) float f32x4;
typedef __attribute__((ext_vector_type(2))) float f32x2;
typedef unsigned __attribute__((ext_vector_type(2))) u32x2;

__device__ __forceinline__ float sigm(float x){ return 1.0f/(1.0f+__expf(-x)); }
__device__ __forceinline__ float bfu(short s){ return __uint_as_float(((unsigned)(unsigned short)s) << 16); }
__device__ __forceinline__ short f2bf(float x){ __hip_bfloat16 h = __float2bfloat16(x); return *(short*)&h; }

// ---- fp8 e4m3fn decode (hot path) ----
#if __has_builtin(__builtin_amdgcn_cvt_pk_f32_fp8)
#define FP8_DEC2(w, sel) __builtin_amdgcn_cvt_pk_f32_fp8((int)(w), (sel))
#else
__device__ __forceinline__ float fp8dec1(unsigned b){
    unsigned s = b >> 7, e = (b >> 3) & 15, m = b & 7;
    float v = e ? __uint_as_float(((e + 120u) << 23) | (m << 20)) : (float)(int)m * 0.001953125f;
    return s ? -v : v;
}
__device__ __forceinline__ f32x2 FP8_DEC2(unsigned w, int sel){
    unsigned h = sel ? (w >> 16) : (w & 0xFFFFu);
    f32x2 r; r.x = fp8dec1(h & 0xFF); r.y = fp8dec1(h >> 8);
    return r;
}
#endif

// ---- fp8 e4m3fn encode (prologue only, manual RNE) ----
__device__ __forceinline__ unsigned char fp8enc(float x){
    unsigned bits = __float_as_uint(x);
    unsigned s = (bits >> 31) << 7;
    unsigned abits = bits & 0x7FFFFFFFu;
    float a = __uint_as_float(abits);
    if (a >= 448.f) return (unsigned char)(s | 0x7E);
    if (a < 0.0009765625f) return (unsigned char)s;
    int E = (int)(abits >> 23) - 127;
    if (E < -6){
        int q = (int)rintf(a * 512.0f);
        if (q >= 8) return (unsigned char)(s | 0x08);
        return (unsigned char)(s | q);
    }
    unsigned m23 = abits & 0x7FFFFFu;
    unsigned r = (m23 + 0x7FFFFu + ((m23 >> 20) & 1u)) >> 20;
    if (r >= 8){ r = 0; E++; }
    if (E > 8 || (E == 8 && r > 6)) return (unsigned char)(s | 0x7E);
    return (unsigned char)(s | ((unsigned)(E + 7) << 3) | r);
}

// ---- MALL-coherent movement for cross-block data (volatile => sc0 sc1) ----
__device__ __forceinline__ unsigned pkbf(float a, float b){
    unsigned ua = (unsigned)__bfloat16_as_ushort(__float2bfloat16(a));
    unsigned ub = (unsigned)__bfloat16_as_ushort(__float2bfloat16(b));
    return ua | (ub << 16);
}

// ---- dataflow sync: per-block monotone phase flags (64B stride) ----
// flag[b] = pi after block b completes a phase. pi = 3t+1 (P1), 3t+2 (P23), 3t+3 (P4).
__device__ __forceinline__ void arrive(unsigned* bar, unsigned pi){
    asm volatile("s_waitcnt vmcnt(0)" ::: "memory");   // our data stores acked first
    __syncthreads();
    if (threadIdx.x == 0)
        *(volatile unsigned*)(bar + (unsigned)blockIdx.x*16) = pi;
}
// each lane of the calling wave polls ONE flag (flagIdx per-lane), until >= target
__device__ __forceinline__ void wave_wait(unsigned* bar, int flagIdx, unsigned target){
    volatile unsigned* s = (volatile unsigned*)(bar + flagIdx*16);
    while (!__all(*s >= target)) __builtin_amdgcn_s_sleep(1);
    asm volatile("" ::: "memory");
}
// one wave sweeps all 256 flags (4 per lane)
__device__ __forceinline__ void wave_wait_all(unsigned* bar, unsigned target){
    int l = threadIdx.x & 63;
    volatile unsigned* s0 = (volatile unsigned*)(bar + l*16);
    volatile unsigned* s1 = (volatile unsigned*)(bar + (l+64)*16);
    volatile unsigned* s2 = (volatile unsigned*)(bar + (l+128)*16);
    volatile unsigned* s3 = (volatile unsigned*)(bar + (l+192)*16);
    for (;;){
        unsigned a = *s0, b = *s1, c = *s2, d = *s3;
        unsigned mn = min(min(a,b), min(c,d));
        if (__all(mn >= target)) break;
        __builtin_amdgcn_s_sleep(1);
    }
    asm volatile("" ::: "memory");
}

// ---------- sort + nAct table ----------
__global__ void k_sort(const int* lens, int* idx, int* rank, unsigned* barCnt, int* nAct){
    __shared__ int L[B];
    int i = threadIdx.x;
    L[i] = lens[i];
    for (int s = i; s < 256; s += B) barCnt[s*16] = 0u;
    __syncthreads();
    int li = L[i];
    int r = 0;
    for (int j = 0; j < B; ++j){
        int lj = L[j];
        if (lj > li || (lj == li && j < i)) r++;
    }
    rank[i] = r;
    idx[r] = i;
    for (int tt = i; tt < T; tt += B){
        int c = 0;
        for (int j = 0; j < B; ++j) c += (L[j] > tt) ? 1 : 0;
        nAct[tt] = c;
    }
}

// ---------- init h0/c0 (sorted) + bf16 copy into hbR slot 0 ----------
__global__ void k_init_hc(const float* enc_h, const float* enc_c, const int* idx,
                          float* h, float* c, __hip_bfloat16* hbR0){
    int j = blockIdx.x;
    int o = idx[j];
    for (int k = threadIdx.x; k < HID; k += blockDim.x){
        float hv = (k < 512) ? enc_h[o*512 + k] : enc_h[B*512 + o*512 + (k-512)];
        float cv = (k < 512) ? enc_c[o*512 + k] : enc_c[B*512 + o*512 + (k-512)];
        h[j*HID + k] = hv;
        c[j*HID + k] = cv;
        hbR0[j*HID + k] = __float2bfloat16(hv);
    }
}

// ---------- Wcat in per-strip MFMA-fragment order (once) ----------
__global__ void k_cvt_wcat(const float* Wih, const float* Whh, __hip_bfloat16* Wfrag){
    size_t i = (size_t)blockIdx.x*256 + threadIdx.x;
    int e = (int)(i & 7);
    size_t t2 = i >> 3;
    int lane = (int)(t2 & 63);
    size_t t3 = t2 >> 6;
    int kt = (int)(t3 % KT4);
    int strip = (int)(t3 / KT4);
    int n = strip*16 + (lane & 15);
    int r = (n & 3)*HID + (n >> 2);
    int k = kt*32 + (lane >> 4)*8 + e;
    float v = (k < EMB+ENC) ? Wih[(size_t)r*(EMB+ENC) + k]
                            : Whh[(size_t)r*HID + (k - EMB - ENC)];
    Wfrag[i] = __float2bfloat16(v);
}

__global__ void k_bsum(const float* bih, const float* bhh, float* bsum){
    int n = blockIdx.x*256 + threadIdx.x;
    int r = (n & 3)*HID + (n >> 2);
    bsum[n] = bih[r] + bhh[r];
}

__global__ void k_cvt_w2(const float* Wda, const float* bda, const float* Wfb, const float* bfb,
                         __hip_bfloat16* W2, float* bias2){
    int n = blockIdx.x;
    const float* src = (n < ATT) ? (Wda + (size_t)n*HID) : (Wfb + (size_t)(n-ATT)*HID);
    __hip_bfloat16* dst = W2 + (size_t)n*HID;
    for (int k = threadIdx.x; k < HID; k += 256) dst[k] = __float2bfloat16(src[k]);
    if (threadIdx.x == 0) bias2[n] = (n < ATT) ? bda[n] : bfb[n-ATT];
}

__global__ void k_cvt_emb(const float* emb, __hip_bfloat16* emb_bf){
    size_t i = (size_t)blockIdx.x*256 + threadIdx.x;
    emb_bf[i] = __float2bfloat16(emb[i]);
}

__global__ void k_cvt_wea(const float* Wea, __hip_bfloat16* Wea_bf){
    int n = blockIdx.x;
    for (int k = threadIdx.x; k < ENC; k += 256)
        Wea_bf[(size_t)n*ENC + k] = __float2bfloat16(Wea[(size_t)n*ENC + k]);
}

// img fp32 -> fp8 e4m3 (sorted order)
__global__ void k_cvt_img8(const float* img, const int* idx, unsigned char* img8){
    int j = blockIdx.y;
    int o = idx[j];
    size_t off = (size_t)blockIdx.x*256 + threadIdx.x;
    img8[(size_t)j*P*ENC + off] = fp8enc(img[(size_t)o*P*ENC + off]);
}

// ---------- att1 (once, MFMA): A from fp32 img (gather+cvt), B = Wea_bf ----------
__global__ __launch_bounds__(256) void k_att1m(const float* img, const int* idx,
                                               const __hip_bfloat16* Wea_bf,
                                               const float* bea, __hip_bfloat16* att1w){
    int m0 = blockIdx.x * 64, n0 = blockIdx.y * 64;
    int tid = threadIdx.x, w = tid >> 6, l = tid & 63, lm = l & 15, lk = l >> 4;
    int g = m0 + 16*w + lm;
    int j = g / P, pp2 = g - j*P;
    int o = idx[j];
    const float* af = img + ((size_t)o*P + pp2)*ENC + 8*lk;
    const short* bp = (const short*)Wea_bf + (size_t)(n0 + lm)*ENC + 8*lk;
    f32x4 acc[4];
    #pragma unroll
    for (int nt=0; nt<4; ++nt) acc[nt] = (f32x4){0.f,0.f,0.f,0.f};
    #pragma unroll 4
    for (int kt = 0; kt < ENC/32; ++kt){
        float4 f0 = *(const float4*)(af + kt*32);
        float4 f1 = *(const float4*)(af + kt*32 + 4);
        bf16x8 a;
        a[0]=f2bf(f0.x); a[1]=f2bf(f0.y); a[2]=f2bf(f0.z); a[3]=f2bf(f0.w);
        a[4]=f2bf(f1.x); a[5]=f2bf(f1.y); a[6]=f2bf(f1.z); a[7]=f2bf(f1.w);
        #pragma unroll
        for (int nt=0; nt<4; ++nt){
            bf16x8 bb = *(const bf16x8*)(bp + (size_t)nt*16*ENC + kt*32);
            acc[nt] = __builtin_amdgcn_mfma_f32_16x16x32_bf16(a, bb, acc[nt], 0,0,0);
        }
    }
    #pragma unroll
    for (int nt=0; nt<4; ++nt){
        int n = n0 + nt*16 + lm;
        float bv = bea[n];
        #pragma unroll
        for (int r=0; r<4; ++r){
            int m = m0 + 16*w + 4*lk + r;
            att1w[(size_t)m*ATT + n] = __float2bfloat16(acc[nt][r] + bv);
        }
    }
}

// ---------- persistent cooperative scan ----------
struct SP {
    const __hip_bfloat16 *att1w, *emb_bf, *Wfrag, *W2;
    const unsigned char *img8;
    const float *bsum, *bias2, *wfa, *bfa;
    const int *sent, *idx, *rank, *lens, *nAct;
    float *D2;
    __hip_bfloat16 *gcR, *hbR;     // rotating: gcR[t], hbR[t] (hbR has T+1 slots)
    float *hF0, *hF1, *cW;
    float *outH, *outA;
    unsigned *barCnt;
};

__global__ __launch_bounds__(1024, 4) void k_scan(SP p){
    __shared__ short WcatL[KT4*64*8];          // 114,688 B, fragment-ordered
    __shared__ union {
        struct { float Dp[4][64][17]; float hS[64][4]; int tokL[64], lensL[64], wLs[64]; } gem;
        struct { float att2L[512]; float wfaL[512]; float red[1024]; float aL[208]; float ctxP[8][512]; } p23;
    } sh;

    int b = blockIdx.x, tid = threadIdx.x;
    int w = tid >> 6, l = tid & 63, lm = l & 15, lk = l >> 4;

    // one-time LDS fill (straight copy, frag order)
    {
        const bf16x8* src = (const bf16x8*)((const short*)p.Wfrag + (size_t)b*KT4*64*8);
        bf16x8* dst = (bf16x8*)WcatL;
        #pragma unroll
        for (int i = 0; i < KT4*64/NTHR; ++i) dst[tid + i*NTHR] = src[tid + i*NTHR];
    }
    __syncthreads();

    float bfa0 = p.bfa[0];
    int jj = b & 63, qq = b >> 6;

    for (int t = 0; t < T; ++t){
        const __hip_bfloat16* hbIn = p.hbR + (size_t)t*B*HID;
        __hip_bfloat16*       hbOut = p.hbR + (size_t)(t+1)*B*HID;
        const __hip_bfloat16* gcT  = p.gcR + (size_t)t*B*ENC;
        const float* hFIn = (t & 1) ? p.hF1 : p.hF0;
        float*       hFOut = (t & 1) ? p.hF0 : p.hF1;
        int nAct = p.nAct[t];
        unsigned pi0 = 3u*(unsigned)t;     // P4(t-1) ordinal

        // ---- P1: D2[64][2560] = h_bf @ W2^T + bias2 ; blocks < 160, 4-way K-split ----
        if (b < N2/16){
            int n0 = b*16;
            int rt = w & 3, kq = w >> 2;
            // per-wave wait: only the 64 P4(t-1) blocks owning u in [256kq, 256kq+256)
            wave_wait(p.barCnt, 64*kq + l, pi0);
            if (16*rt < nAct){
                const short* ap = (const short*)hbIn + (size_t)(16*rt + lm)*HID + kq*256 + 8*lk;
                const short* bp = (const short*)p.W2 + (size_t)(n0 + lm)*HID + kq*256 + 8*lk;
                f32x4 acc = {0.f,0.f,0.f,0.f};
                #pragma unroll
                for (int kt = 0; kt < 8; ++kt){
                    bf16x8 a = *(const bf16x8*)(ap + kt*32);
                    bf16x8 bb = *(const bf16x8*)(bp + kt*32);
                    acc = __builtin_amdgcn_mfma_f32_16x16x32_bf16(a, bb, acc, 0,0,0);
                }
                #pragma unroll
                for (int r=0; r<4; ++r) sh.gem.Dp[kq][16*rt + 4*lk + r][lm] = acc[r];
            }
            __syncthreads();
            // vectorized 16B coherent store of D2
            if (tid < 256){
                int m = tid >> 2, c4 = (tid & 3)*4;
                if (m < nAct){
                    f32x4 v;
                    #pragma unroll
                    for (int z=0; z<4; ++z){
                        int nl = c4 + z;
                        v[z] = sh.gem.Dp[0][m][nl] + sh.gem.Dp[1][m][nl]
                             + sh.gem.Dp[2][m][nl] + sh.gem.Dp[3][m][nl] + p.bias2[n0 + nl];
                    }
                    *(volatile f32x4*)(&p.D2[m*N2 + n0 + c4]) = v;
                }
            }
            arrive(p.barCnt, pi0 + 1u);     // blocks < 160 only
        }

        // ---- P23 producer wait: ALL blocks (also guarantees hbR[t] fully visible
        //      before ANY normal-cached read of it in the P4 prelude) ----
        if (w == 0){
            int fi = (l < 32) ? l : (32*qq + l);
            wave_wait(p.barCnt, fi, pi0 + 1u);
        }
        __syncthreads();

        // ---- P23: e + softmax + context + gc ; block = (j=b&63, q=b>>6) ----
        int ljj = p.lens[p.idx[jj]];
        int wjj = p.rank[jj];
        if (t < ljj){
            if (tid < 128){
                f32x4 v = *(const volatile f32x4*)(&p.D2[jj*N2 + tid*4]);
                *(f32x4*)(&sh.p23.att2L[tid*4]) = v;
            }
            if (tid < 512) sh.p23.wfaL[tid] = p.wfa[tid];
            __syncthreads();

            int pp = tid & 255, ah = tid >> 8;
            float acc = 0.f;
            if (pp < P){
                const short* ar = (const short*)p.att1w + (size_t)(jj*P + pp)*ATT + ah*128;
                #pragma unroll 8
                for (int k8 = 0; k8 < 16; ++k8){
                    bf16x8 v = *(const bf16x8*)(ar + k8*8);
                    #pragma unroll
                    for (int z=0; z<8; ++z){
                        int a = ah*128 + k8*8 + z;
                        acc += fmaxf(bfu(v[z]) + sh.p23.att2L[a], 0.f) * sh.p23.wfaL[a];
                    }
                }
            }
            sh.p23.red[tid] = acc;
            __syncthreads();
            float e = -1e30f;
            if (tid < P) e = sh.p23.red[tid] + sh.p23.red[tid+256] + sh.p23.red[tid+512] + sh.p23.red[tid+768] + bfa0;
            // wave-level softmax reduce (waves 0..3 hold the 256 row-slots)
            float* sm  = &sh.p23.red[976];
            float* sm2 = &sh.p23.red[984];
            if (tid < 256){
                float mv = e;
                #pragma unroll
                for (int off = 32; off; off >>= 1) mv = fmaxf(mv, __shfl_xor(mv, off, 64));
                if (l == 0) sm[w] = mv;
            }
            __syncthreads();
            float m = fmaxf(fmaxf(sm[0], sm[1]), fmaxf(sm[2], sm[3]));
            float ex = (tid < P) ? __expf(e - m) : 0.f;
            if (tid < 256){
                float sv = ex;
                #pragma unroll
                for (int off = 32; off; off >>= 1) sv += __shfl_xor(sv, off, 64);
                if (l == 0) sm2[w] = sv;
            }
            __syncthreads();
            float ssum = sm2[0] + sm2[1] + sm2[2] + sm2[3];
            if (tid < P) sh.p23.aL[tid] = ex / ssum;
            if (tid >= P && tid < 208) sh.p23.aL[tid] = 0.f;
            __syncthreads();

            // context quarter [q*512, q*512+512) from fp8 img: wave w takes p = w, w+16, ...
            const unsigned char* ib = p.img8 + (size_t)jj*P*ENC + qq*512 + l*8;
            float a8[8];
            #pragma unroll
            for (int z=0; z<8; ++z) a8[z] = 0.f;
            #pragma unroll 4
            for (int i = 0; i < 13; ++i){
                int pp2 = w + 16*i;
                int pr = (pp2 < P) ? pp2 : 0;
                u32x2 v = *(const u32x2*)(ib + (size_t)pr*ENC);
                float al = sh.p23.aL[pp2];
                f32x2 f01 = FP8_DEC2(v.x, 0);
                f32x2 f23 = FP8_DEC2(v.x, 1);
                f32x2 f45 = FP8_DEC2(v.y, 0);
                f32x2 f67 = FP8_DEC2(v.y, 1);
                a8[0] += al * f01.x; a8[1] += al * f01.y;
                a8[2] += al * f23.x; a8[3] += al * f23.y;
                a8[4] += al * f45.x; a8[5] += al * f45.y;
                a8[6] += al * f67.x; a8[7] += al * f67.y;
            }
            if (w < 8){
                #pragma unroll
                for (int z=0; z<8; ++z) sh.p23.ctxP[w][l*8+z] = a8[z];
            }
            __syncthreads();
            if (w >= 8){
                #pragma unroll
                for (int z=0; z<8; ++z) sh.p23.ctxP[w-8][l*8+z] += a8[z];
            }
            __syncthreads();
            // vectorized gc: 128 threads x (16B gate read + 8B gc store)
            if (tid < 128){
                int d0 = 4*tid;
                f32x4 gv = *(const volatile f32x4*)(&p.D2[jj*N2 + ATT + qq*512 + d0]);
                float c0=0.f, c1=0.f, c2=0.f, c3=0.f;
                #pragma unroll
                for (int r=0; r<8; ++r){
                    c0 += sh.p23.ctxP[r][d0];   c1 += sh.p23.ctxP[r][d0+1];
                    c2 += sh.p23.ctxP[r][d0+2]; c3 += sh.p23.ctxP[r][d0+3];
                }
                u32x2 pk;
                pk.x = pkbf(sigm(gv[0])*c0, sigm(gv[1])*c1);
                pk.y = pkbf(sigm(gv[2])*c2, sigm(gv[3])*c3);
                *(volatile u32x2*)((short*)gcT + jj*ENC + qq*512 + d0) = pk;
            }
        }
        arrive(p.barCnt, pi0 + 2u);     // gc visible; independent work in the wait shadow

        // outA write (external-only) in barrier shadow
        if (qq == 0 && tid < P){
            float av = (t < ljj) ? sh.p23.aL[tid] : 0.f;
            p.outA[((size_t)(wjj*T + t))*P + tid] = av;
        }
        __syncthreads();               // close p23 LDS usage before gem reuse

        // ---- P4 prelude + non-gc MFMA (emb + h segments) in barrier shadow ----
        if (tid < 64){
            int o = p.idx[tid];
            sh.gem.tokL[tid] = p.sent[o*T + t];
            sh.gem.lensL[tid] = p.lens[o];
            sh.gem.wLs[tid] = p.rank[tid];
        }
        __syncthreads();
        {
            int rt = w & 3, kq = w >> 2;
            bool act = (16*rt < nAct);
            int mrow = 16*rt + lm;
            f32x4 acc = {0.f,0.f,0.f,0.f};
            const short* aEmb = 0; const short* aGc = 0; const short* aH = 0;
            const bf16x8* BL = (const bf16x8*)WcatL;
            if (act){
                int tok = sh.gem.tokL[mrow];
                aEmb = (const short*)p.emb_bf + (size_t)tok*EMB + 8*lk;
                aGc  = (const short*)gcT + (size_t)mrow*ENC + 8*lk;
                aH   = (const short*)hbIn + (size_t)mrow*HID + 8*lk;
                if (kq == 0){
                    #pragma unroll 8
                    for (int kt = 0; kt < 16; ++kt){
                        bf16x8 a = *(const bf16x8*)(aEmb + kt*32);
                        acc = __builtin_amdgcn_mfma_f32_16x16x32_bf16(a, BL[kt*64 + l], acc, 0,0,0);
                    }
                } else if (kq == 2){
                    #pragma unroll
                    for (int kt = 80; kt < 84; ++kt){
                        bf16x8 a = *(const bf16x8*)(aH + (kt-80)*32);
                        acc = __builtin_amdgcn_mfma_f32_16x16x32_bf16(a, BL[kt*64 + l], acc, 0,0,0);
                    }
                } else if (kq == 3){
                    #pragma unroll 7
                    for (int kt = 84; kt < 112; ++kt){
                        bf16x8 a = *(const bf16x8*)(aH + (kt-80)*32);
                        acc = __builtin_amdgcn_mfma_f32_16x16x32_bf16(a, BL[kt*64 + l], acc, 0,0,0);
                    }
                }
            }
            // full wait: P4 needs all 256 gc producers
            if (tid < 64) wave_wait_all(p.barCnt, pi0 + 2u);
            __syncthreads();

            if (act){
                if (kq == 0){
                    #pragma unroll 6
                    for (int kt = 16; kt < 28; ++kt){
                        bf16x8 a = *(const bf16x8*)(aGc + (kt-16)*32);
                        acc = __builtin_amdgcn_mfma_f32_16x16x32_bf16(a, BL[kt*64 + l], acc, 0,0,0);
                    }
                } else if (kq == 1){
                    #pragma unroll 7
                    for (int kt = 28; kt < 56; ++kt){
                        bf16x8 a = *(const bf16x8*)(aGc + (kt-16)*32);
                        acc = __builtin_amdgcn_mfma_f32_16x16x32_bf16(a, BL[kt*64 + l], acc, 0,0,0);
                    }
                } else if (kq == 2){
                    #pragma unroll 6
                    for (int kt = 56; kt < 80; ++kt){
                        bf16x8 a = *(const bf16x8*)(aGc + (kt-16)*32);
                        acc = __builtin_amdgcn_mfma_f32_16x16x32_bf16(a, BL[kt*64 + l], acc, 0,0,0);
                    }
                }
                #pragma unroll
                for (int r=0; r<4; ++r) sh.gem.Dp[kq][16*rt + 4*lk + r][lm] = acc[r];
            }
        }
        __syncthreads();

        // ---- LSTM pointwise ----
        int j2 = tid & 63, du = tid >> 6;
        int u = 4*b + du;
        float cNew = 0.f, hNew = 0.f, hKeep = 0.f, cOld = 0.f;
        bool active = false;
        if (tid < 256){
            float g4[4];
            #pragma unroll
            for (int g=0; g<4; ++g){
                int nl = 4*du + g;
                g4[g] = sh.gem.Dp[0][j2][nl] + sh.gem.Dp[1][j2][nl]
                      + sh.gem.Dp[2][j2][nl] + sh.gem.Dp[3][j2][nl] + p.bsum[16*b + nl];
            }
            float ig = sigm(g4[0]), fg = sigm(g4[1]), gg = tanhf(g4[2]), og = sigm(g4[3]);
            cOld = p.cW[j2*HID + u];
            cNew = fg*cOld + ig*gg;
            hNew = og*tanhf(cNew);
            active = (t < sh.gem.lensL[j2]);
            float hOld = hFIn[j2*HID + u];
            hKeep = active ? hNew : hOld;
            sh.gem.hS[j2][du] = hKeep;
        }
        __syncthreads();
        // vectorized 8B coherent store of h(t+1): 64 threads
        if (tid < 64){
            u32x2 pk;
            pk.x = pkbf(sh.gem.hS[tid][0], sh.gem.hS[tid][1]);
            pk.y = pkbf(sh.gem.hS[tid][2], sh.gem.hS[tid][3]);
            *(volatile u32x2*)((short*)hbOut + tid*HID + 4*b) = pk;
        }
        arrive(p.barCnt, pi0 + 3u);    // h(t+1) visible; private/external stores in shadow
        if (tid < 256){
            p.cW[j2*HID + u] = active ? cNew : cOld;
            hFOut[j2*HID + u] = hKeep;
            p.outH[((size_t)sh.gem.wLs[j2]*T + t)*HID + u] = active ? hNew : 0.f;
        }
        // no full wait here: next step's consumers do their own producer-subset waits
    }
}

extern "C" void kernel_launch(void* const* d_in, const int* in_sizes, int n_in,
                              void* d_out, int out_size, void* d_ws, size_t ws_size,
                              hipStream_t stream) {
    const float* img   = (const float*)d_in[0];
    const int*   sent  = (const int*)  d_in[1];
    const float* enc_h = (const float*)d_in[2];
    const float* enc_c = (const float*)d_in[3];
    const int*   lens  = (const int*)  d_in[4];
    const float* emb   = (const float*)d_in[5];
    const float* Wea   = (const float*)d_in[6];
    const float* bea   = (const float*)d_in[7];
    const float* Wda   = (const float*)d_in[8];
    const float* bda   = (const float*)d_in[9];
    const float* wfa   = (const float*)d_in[10];
    const float* bfa   = (const float*)d_in[11];
    const float* Wfb   = (const float*)d_in[12];
    const float* bfb   = (const float*)d_in[13];
    const float* Wih   = (const float*)d_in[14];
    const float* bih   = (const float*)d_in[15];
    const float* Whh   = (const float*)d_in[16];
    const float* bhh   = (const float*)d_in[17];

    float* outH = (float*)d_out;                       // [B,T,HID] f32
    float* outA = outH + (size_t)B*T*HID;              // [B,T,P]  f32

    char* wsb = (char*)d_ws;
    size_t off = 0;
    int* idxW  = (int*)(wsb + off); off += 256;
    int* rankW = (int*)(wsb + off); off += 256;
    int* nActW = (int*)(wsb + off); off += 1024;
    unsigned* barCnt = (unsigned*)(wsb + off); off += 32768;   // 256 flags x 64B (+pad)
    __hip_bfloat16* att1w = (__hip_bfloat16*)(wsb + off); off += (size_t)B*P*ATT*2;       // 12.85MB
    unsigned char* img8 = (unsigned char*)(wsb + off); off += (size_t)B*P*ENC;            // 25.69MB (fp8)
    __hip_bfloat16* emb_bf= (__hip_bfloat16*)(wsb + off); off += (size_t)10000*EMB*2;     // 10.24MB
    __hip_bfloat16* Wfrag = (__hip_bfloat16*)(wsb + off); off += (size_t)4*HID*KTOT*2;    // 29.36MB
    __hip_bfloat16* W2    = (__hip_bfloat16*)(wsb + off); off += (size_t)N2*HID*2;        // 5.24MB
    __hip_bfloat16* Wea_bf= (__hip_bfloat16*)(wsb + off); off += (size_t)ATT*ENC*2;       // 2.10MB (prologue-only)
    float* bsum  = (float*)(wsb + off); off += 4*HID*4;
    float* bias2 = (float*)(wsb + off); off += N2*4;
    float* hA    = (float*)(wsb + off); off += B*HID*4;
    float* hB    = (float*)(wsb + off); off += B*HID*4;
    float* cWs   = (float*)(wsb + off); off += B*HID*4;
    float* D2    = (float*)(wsb + off); off += (size_t)B*N2*4;
    __hip_bfloat16* gcR = (__hip_bfloat16*)(wsb + off); off += (size_t)T*B*ENC*2;         // 41.9MB rotating
    __hip_bfloat16* hbR = (__hip_bfloat16*)(wsb + off); off += (size_t)(T+1)*B*HID*2;     // 21.1MB rotating

    k_sort<<<1, 64, 0, stream>>>(lens, idxW, rankW, barCnt, nActW);
    k_init_hc<<<B, 256, 0, stream>>>(enc_h, enc_c, idxW, hA, cWs, hbR);
    k_cvt_wcat<<<57344, 256, 0, stream>>>(Wih, Whh, Wfrag);
    k_bsum<<<16, 256, 0, stream>>>(bih, bhh, bsum);
    k_cvt_w2<<<N2, 256, 0, stream>>>(Wda, bda, Wfb, bfb, W2, bias2);
    k_cvt_emb<<<20000, 256, 0, stream>>>(emb, emb_bf);
    k_cvt_wea<<<ATT, 256, 0, stream>>>(Wea, Wea_bf);
    k_cvt_img8<<<dim3(P*ENC/256, B), 256, 0, stream>>>(img, idxW, img8);
    k_att1m<<<dim3((B*P)/64, ATT/64), 256, 0, stream>>>(img, idxW, Wea_bf, bea, att1w);

    SP sp;
    sp.att1w = att1w; sp.img8 = img8; sp.emb_bf = emb_bf; sp.Wfrag = Wfrag; sp.W2 = W2;
    sp.bsum = bsum; sp.bias2 = bias2; sp.wfa = wfa; sp.bfa = bfa;
    sp.sent = sent; sp.idx = idxW; sp.rank = rankW; sp.lens = lens; sp.nAct = nActW;
    sp.D2 = D2; sp.gcR = gcR; sp.hbR = hbR;
    sp.hF0 = hA; sp.hF1 = hB; sp.cW = cWs;
    sp.outH = outH; sp.outA = outA;
    sp.barCnt = barCnt;

    void* args[] = { &sp };
    hipLaunchCooperativeKernel(reinterpret_cast<void*>(k_scan), dim3(NBLK), dim3(NTHR),
                               args, 0, stream);
}